// Round 13
// baseline (911.872 us; speedup 1.0000x reference)
//
#include <hip/hip_runtime.h>
#include <hip/hip_fp16.h>

#define Hn 128
#define Wn 128
#define HWn 16384
#define Cn 64
#define Bn 8
#define NTOT (Bn*Cn*HWn)   /* 8388608 */
#define NPIX (Bn*HWn)      /* 131072  */
#define DTc 0.3f
#define EPSc 1e-5f

__device__ __forceinline__ float sigm(float t){ return 1.0f/(1.0f+__expf(-t)); }

// ---------------- F = force + 0.2*illum (fp16) + fused oscillator step 0 ----------------
__global__ void fuseF0(const float4* __restrict__ force, const float4* __restrict__ illum,
                       __half* __restrict__ F, __half* __restrict__ XA, __half* __restrict__ V)
{
    int i = blockIdx.x * blockDim.x + threadIdx.x;      // NTOT/4 threads
    float4 f = force[i], il = illum[i];
    float a0 = f.x + 0.2f*il.x, a1 = f.y + 0.2f*il.y;
    float a2 = f.z + 0.2f*il.z, a3 = f.w + 0.2f*il.w;
    uint2 pf, px, pv;
    __half2 h;
    h = __floats2half2_rn(a0, a1);            pf.x = *(unsigned int*)&h;
    h = __floats2half2_rn(a2, a3);            pf.y = *(unsigned int*)&h;
    h = __floats2half2_rn(0.09f*a0, 0.09f*a1); px.x = *(unsigned int*)&h;
    h = __floats2half2_rn(0.09f*a2, 0.09f*a3); px.y = *(unsigned int*)&h;
    h = __floats2half2_rn(0.3f*a0, 0.3f*a1);   pv.x = *(unsigned int*)&h;
    h = __floats2half2_rn(0.3f*a2, 0.3f*a3);   pv.y = *(unsigned int*)&h;
    *reinterpret_cast<uint2*>(F  + 4*(size_t)i) = pf;
    *reinterpret_cast<uint2*>(XA + 4*(size_t)i) = px;
    *reinterpret_cast<uint2*>(V  + 4*(size_t)i) = pv;
}

// ---------------- prep: style constant + weight transposes + packed w3 pairs ------------
__global__ void prep(const float* __restrict__ style, const float* __restrict__ w1,
                     const float* __restrict__ b1, const float* __restrict__ pw,
                     const float* __restrict__ pw1, const float* __restrict__ pw2,
                     const float* __restrict__ w3, const float* __restrict__ b3,
                     float* __restrict__ w1T, float* __restrict__ c1,
                     float* __restrict__ pwT, float* __restrict__ pw1T,
                     float* __restrict__ pw2T,
                     __half2* __restrict__ w3abP, __half2* __restrict__ w3gbP,
                     __half2* __restrict__ b3abP, __half2* __restrict__ b3gbP)
{
    int t = threadIdx.x;
    if (t < 32) {
        float s = b1[t];
        for (int k = 0; k < 64; k++) s += w1[t*128 + 64 + k] * style[k];
        c1[t] = s;
    }
    for (int i = t; i < 2048; i += 256) { int c = i >> 5, j = i & 31; w1T[i] = w1[j*128 + c]; }
    for (int i = t; i < 4096; i += 256) {
        int c = i >> 6, k = i & 63;
        pwT[i]  = pw[k*64 + c];
        pw1T[i] = pw1[k*64 + c];
        pw2T[i] = pw2[k*64 + c];
    }
    for (int i = t; i < 2048; i += 256) {
        int j = i >> 5, k = i & 31;
        w3abP[i] = __floats2half2_rn(w3[j*32 + k],         w3[(64 + j)*32 + k]);
        w3gbP[i] = __floats2half2_rn(w3[(128 + j)*32 + k], w3[(192 + j)*32 + k]);
    }
    if (t < 64) {
        b3abP[t] = __floats2half2_rn(b3[t],       b3[64 + t]);
        b3gbP[t] = __floats2half2_rn(b3[128 + t], b3[192 + t]);
    }
}

// ---------------- hyper encoder: 2-way split + F staged in LDS ----------------
// y=0 -> AB, y=1 -> GB. Block = 256 px, stages F[64ch][256px] (32 KB).
__global__ __launch_bounds__(256)
void hyperS(const __half* __restrict__ F,
            const float* __restrict__ w1T, const float* __restrict__ c1,
            const float* __restrict__ w2, const float* __restrict__ b2,
            const __half2* __restrict__ w3abP, const __half2* __restrict__ w3gbP,
            const __half2* __restrict__ b3abP, const __half2* __restrict__ b3gbP,
            __half2* __restrict__ AB, __half2* __restrict__ GB)
{
    __shared__ __half fs[64][256];
    int t = threadIdx.x;
    int p0 = blockIdx.x << 8;
    int b  = p0 >> 14;
    int sp0 = p0 & (HWn - 1);
    int tbase = b * Cn * HWn + sp0;

    // stage F tile: 2048 uint4, 8 per thread, coalesced
#pragma unroll
    for (int it = 0; it < 8; it++) {
        int f = t + (it << 8);
        int c = f >> 5, u = f & 31;
        uint4 d = *reinterpret_cast<const uint4*>(F + tbase + c*HWn + (u << 3));
        *reinterpret_cast<uint4*>(&fs[c][u << 3]) = d;
    }
    __syncthreads();

    int base = tbase + t;

    float u1[32];
#pragma unroll
    for (int j = 0; j < 32; j++) u1[j] = c1[j];
#pragma unroll 4
    for (int c = 0; c < 64; c++) {
        float fc = __half2float(fs[c][t]);
        const float* __restrict__ wr = w1T + c*32;
#pragma unroll
        for (int j = 0; j < 32; j++) u1[j] += wr[j] * fc;
    }
#pragma unroll
    for (int j = 0; j < 32; j++) { float v = u1[j]; u1[j] = v > 0.f ? v : 0.2f*v; }

    float u2[32];
#pragma unroll
    for (int i = 0; i < 32; i++) {
        float s = b2[i];
#pragma unroll
        for (int j = 0; j < 32; j++) s += w2[i*32 + j] * u1[j];
        u2[i] = s > 0.f ? s : 0.2f*s;
    }
    __half2 u2b[32];
#pragma unroll
    for (int i = 0; i < 32; i++) u2b[i] = __half2half2(__float2half(u2[i]));

    if (blockIdx.y == 0) {
#pragma unroll 2
        for (int j = 0; j < 64; j++) {
            __half2 aab = b3abP[j];
            const __half2* __restrict__ wa = w3abP + j*32;
#pragma unroll
            for (int i = 0; i < 32; i++) aab = __hfma2(wa[i], u2b[i], aab);
            float2 tab = __half22float2(aab);
            float om = 2.0f * sigm(tab.x);
            float ze = sigm(tab.y);
            AB[base + j*HWn] = __floats2half2_rn(2.0f * ze * om, om * om);
        }
    } else {
#pragma unroll 2
        for (int j = 0; j < 64; j++) {
            __half2 agb = b3gbP[j];
            const __half2* __restrict__ wg = w3gbP + j*32;
#pragma unroll
            for (int i = 0; i < 32; i++) agb = __hfma2(wg[i], u2b[i], agb);
            float2 tgb = __half22float2(agb);
            GB[base + j*HWn] = __floats2half2_rn(2.0f * sigm(tgb.x), tanhf(tgb.y));
        }
    }
}

// ---------------- oscillator step v2: LDS-staged X, block = 64 px (half row) x 64 ch ----
// XCD swizzle: wid&7 owns contiguous 1/8 of half-row space.
template <bool LAST>
__global__ __launch_bounds__(256)
void osc_step(const __half* __restrict__ Xin, __half* __restrict__ Xout,
              __half* __restrict__ V, const __half* __restrict__ F,
              const __half2* __restrict__ AB,
              const float* __restrict__ dwk, const float* __restrict__ pwT,
              float* __restrict__ Xf, float* __restrict__ Vf)
{
    __shared__ __half xs[64][3][68];           // [ch][row][1 halo + 64 core(+2 off) + 1 halo]
    int wid = blockIdx.x;
    int hp  = ((wid & 7) << 8) + (wid >> 3);   // half-row id, 2048 = 8*256
    int b   = hp >> 8;
    int hr  = hp & 255;
    int y   = hr >> 1;
    int xh  = (hr & 1) << 6;
    int t   = threadIdx.x;
    int base0 = b * Cn * HWn + y * Wn + xh;    // element index of (ch0, px0)

    int   yo[3] = { y > 0 ? -Wn : 0, 0, y < Hn-1 ? Wn : 0 };
    float my[3] = { y > 0 ? 1.f : 0.f, 1.f, y < Hn-1 ? 1.f : 0.f };

    // stage core: 64ch x 3row x 32 uint (2px) = 6144 uints, 24/thread, coalesced
#pragma unroll
    for (int it = 0; it < 24; it++) {
        int f = t + (it << 8);
        int c = f / 96;
        int rem = f - c*96;
        int r = rem >> 5;
        int u = rem & 31;
        unsigned int d = *reinterpret_cast<const unsigned int*>(Xin + base0 + c*HWn + yo[r] + (u << 1));
        *reinterpret_cast<unsigned int*>(&xs[c][r][2 + (u << 1)]) = d;
    }
    // stage halo: 64ch x 3row x 2 sides = 384 scalars (values masked at image edges later)
    for (int hv = t; hv < 384; hv += 256) {
        int c = hv / 6;
        int rem = hv - c*6;
        int r = rem >> 1;
        int side = rem & 1;
        xs[c][r][side ? 66 : 1] = Xin[base0 + c*HWn + yo[r] + (side ? 64 : -1)];
    }
    __syncthreads();

    int l  = t & 63;
    int c0 = (t >> 6) << 4;                    // wave-uniform channel group
    int x  = xh + l;
    float wl = x > 0      ? 1.f : 0.f;
    float wr = x < Wn - 1 ? 1.f : 0.f;

    // pointwise coupling from LDS
    float acc[16];
#pragma unroll
    for (int k = 0; k < 16; k++) acc[k] = 0.f;
#pragma unroll 4
    for (int c = 0; c < 64; c++) {
        float xc = __half2float(xs[c][1][2 + l]);
        const float* __restrict__ wrow = pwT + c*64 + c0;
#pragma unroll
        for (int k = 0; k < 16; k++) acc[k] += wrow[k] * xc;
    }

#pragma unroll
    for (int cc = 0; cc < 16; cc++) {
        int c = c0 + cc;
        int cb = base0 + l + c*HWn;
        float dws = 0.f;
#pragma unroll
        for (int r = 0; r < 3; r++) {
            float lf = __half2float(xs[c][r][1 + l]);
            float ct = __half2float(xs[c][r][2 + l]);
            float rt = __half2float(xs[c][r][3 + l]);
            float k0 = dwk[c*9 + r*3 + 0] * my[r];
            float k1 = dwk[c*9 + r*3 + 1] * my[r];
            float k2 = dwk[c*9 + r*3 + 2] * my[r];
            dws += k0 * (wl * lf) + k1 * ct + k2 * (wr * rt);
        }
        float xc = __half2float(xs[c][1][2 + l]);
        float2 ab = __half22float2(AB[cb]);
        float vv = __half2float(V[cb]);
        float accel = __half2float(F[cb]) + acc[cc] + dws - ab.x * vv - ab.y * xc;
        vv += accel * DTc;
        float xn = xc + vv * DTc;
        if constexpr (!LAST) {
            V[cb] = __float2half(vv);
            Xout[cb] = __float2half(xn);
        } else {
            Xf[cb] = xn;
            Vf[cb] = vv;
        }
    }
}

// ---------------- instance norm stats ----------------
__global__ void inorm_stats(const __half* __restrict__ F, const float* __restrict__ X,
                            float* __restrict__ mu, float* __restrict__ rs)
{
    int bc = blockIdx.x;             // 0..511
    int base = bc * HWn;
    const __half2* __restrict__ F2 = (const __half2*)(F + base);
    const float4*  __restrict__ X4 = (const float4*)(X + base);
    float s = 0.f, s2 = 0.f;
    for (int i = threadIdx.x; i < HWn/4; i += blockDim.x) {
        float4 xv = X4[i];
        float2 f0 = __half22float2(F2[2*i]);
        float2 f1 = __half22float2(F2[2*i+1]);
        float v0 = f0.x + xv.x, v1 = f0.y + xv.y, v2 = f1.x + xv.z, v3 = f1.y + xv.w;
        s += (v0 + v1) + (v2 + v3);
        s2 += (v0*v0 + v1*v1) + (v2*v2 + v3*v3);
    }
#pragma unroll
    for (int o = 32; o > 0; o >>= 1) { s += __shfl_down(s, o); s2 += __shfl_down(s2, o); }
    __shared__ float sh[16];
    int w = threadIdx.x >> 6, l = threadIdx.x & 63;
    if (l == 0) { sh[w] = s; sh[8 + w] = s2; }
    __syncthreads();
    if (threadIdx.x == 0) {
        float S = 0.f, S2 = 0.f;
        for (int i = 0; i < 4; i++) { S += sh[i]; S2 += sh[8 + i]; }
        float m = S / (float)HWn;
        float var = S2 / (float)HWn - m*m;
        mu[bc] = m;
        rs[bc] = rsqrtf(var + EPSc);
    }
}

// ---------------- instance norm apply + style modulation -> out_pre (fp16) ----------------
__global__ void modulate(const __half* __restrict__ F, const float4* __restrict__ X4,
                         const uint4* __restrict__ GBu, const float* __restrict__ mu,
                         const float* __restrict__ rs, __half* __restrict__ outp)
{
    int e4 = blockIdx.x * blockDim.x + threadIdx.x;   // NTOT/4 threads
    int bc = e4 >> 12;                                // (e4*4) >> 14
    float m = mu[bc], r = rs[bc];
    uint2 fu = *reinterpret_cast<const uint2*>(F + 4*(size_t)e4);
    float2 f0 = __half22float2(*(__half2*)&fu.x);
    float2 f1 = __half22float2(*(__half2*)&fu.y);
    float4 xv = X4[e4];
    uint4 gb = GBu[e4];
    float2 g0 = __half22float2(*(__half2*)&gb.x);
    float2 g1 = __half22float2(*(__half2*)&gb.y);
    float2 g2 = __half22float2(*(__half2*)&gb.z);
    float2 g3 = __half22float2(*(__half2*)&gb.w);
    float o0 = g0.x * ((f0.x + xv.x - m) * r) + g0.y;
    float o1 = g1.x * ((f0.y + xv.y - m) * r) + g1.y;
    float o2 = g2.x * ((f1.x + xv.z - m) * r) + g2.y;
    float o3 = g3.x * ((f1.y + xv.w - m) * r) + g3.y;
    __half2 h01 = __floats2half2_rn(o0, o1);
    __half2 h23 = __floats2half2_rn(o2, o3);
    uint2 pack; pack.x = *(unsigned int*)&h01; pack.y = *(unsigned int*)&h23;
    *reinterpret_cast<uint2*>(outp + 4*(size_t)e4) = pack;
}

// ---------------- refine v3: one row/block, 2 px x 8 ch per thread, b128 weight reads ----
__global__ __launch_bounds__(512)
void refine(const __half* __restrict__ outp,
            const float* __restrict__ rdwk, const float* __restrict__ rdwb,
            const float* __restrict__ pw1T, const float* __restrict__ pb1,
            const float* __restrict__ pw2T, const float* __restrict__ pb2,
            const float* __restrict__ ls, float* __restrict__ out)
{
    __shared__ unsigned int rv2_s[64][64];
    __shared__ unsigned int act2_s[64][64];
    __shared__ __half w1s[64][64];
    __shared__ __half w2s[64][64];
    __shared__ float  dwks[576];
    __shared__ __half2 pb1h[32], pb2h[32];
    __shared__ float  rdwbs[64], lss[64];
    int t = threadIdx.x;
    for (int i = t; i < 4096; i += 512) {
        w1s[i>>6][i&63] = __float2half(pw1T[i]);
        w2s[i>>6][i&63] = __float2half(pw2T[i]);
    }
    for (int i = t; i < 576; i += 512) dwks[i] = rdwk[i];
    if (t < 64) { rdwbs[t]=rdwb[t]; lss[t]=ls[t]; }
    if (t < 32) {
        pb1h[t] = __floats2half2_rn(pb1[2*t], pb1[2*t+1]);
        pb2h[t] = __floats2half2_rn(pb2[2*t], pb2[2*t+1]);
    }

    int l  = t & 63;
    int g  = t >> 6;
    int c0 = g << 3;
    int row = blockIdx.x;
    int b = row >> 7, y = row & 127;
    int base = b * Cn * HWn + y * Wn;
    int px0 = l << 1;

    int   yo[3] = { y > 0 ? -Wn : 0, 0, y < Hn-1 ? Wn : 0 };
    float my[3] = { y > 0 ? 1.f : 0.f, 1.f, y < Hn-1 ? 1.f : 0.f };
    float wl = l > 0  ? 1.f : 0.f;
    float wr = l < 63 ? 1.f : 0.f;
    int loff = l > 0 ? -1 : 0;
    __syncthreads();

#pragma unroll
    for (int cc = 0; cc < 8; cc++) {
        int c = c0 + cc;
        int cb = base + c*HWn + px0;
        float rv0 = rdwbs[c], rv1 = rdwbs[c];
#pragma unroll
        for (int r = 0; r < 3; r++) {
            const __half* __restrict__ rp = outp + cb + yo[r];
            unsigned int cu = *reinterpret_cast<const unsigned int*>(rp);
            float2 ct = __half22float2(*(__half2*)&cu);
            float lf = __half2float(rp[loff]);
            float rt = __half2float(rp[2]);
            float k0 = dwks[c*9 + r*3 + 0] * my[r];
            float k1 = dwks[c*9 + r*3 + 1] * my[r];
            float k2 = dwks[c*9 + r*3 + 2] * my[r];
            rv0 += k0*(wl*lf) + k1*ct.x + k2*ct.y;
            rv1 += k0*ct.x + k1*ct.y + k2*(wr*rt);
        }
        __half2 hv = __floats2half2_rn(rv0, rv1);
        rv2_s[c][l] = *(unsigned int*)&hv;
    }
    __syncthreads();

    __half2 accA[4], accB[4];
#pragma unroll
    for (int q = 0; q < 4; q++) { accA[q] = pb1h[(c0 >> 1) + q]; accB[q] = accA[q]; }
#pragma unroll 8
    for (int c = 0; c < 64; c++) {
        unsigned int rvu = rv2_s[c][l];
        __half2 rvp = *(__half2*)&rvu;
        __half2 r0 = __half2half2(__low2half(rvp));
        __half2 r1 = __half2half2(__high2half(rvp));
        uint4 wq = *reinterpret_cast<const uint4*>(&w1s[c][c0]);
        __half2 w01 = *(__half2*)&wq.x, w23 = *(__half2*)&wq.y;
        __half2 w45 = *(__half2*)&wq.z, w67 = *(__half2*)&wq.w;
        accA[0] = __hfma2(w01, r0, accA[0]); accB[0] = __hfma2(w01, r1, accB[0]);
        accA[1] = __hfma2(w23, r0, accA[1]); accB[1] = __hfma2(w23, r1, accB[1]);
        accA[2] = __hfma2(w45, r0, accA[2]); accB[2] = __hfma2(w45, r1, accB[2]);
        accA[3] = __hfma2(w67, r0, accA[3]); accB[3] = __hfma2(w67, r1, accB[3]);
    }
#pragma unroll
    for (int q = 0; q < 4; q++) {
        float2 a0 = __half22float2(accA[q]);
        float2 a1 = __half22float2(accB[q]);
        float e0 = a0.x > 0.f ? a0.x : 0.2f*a0.x;
        float e1 = a0.y > 0.f ? a0.y : 0.2f*a0.y;
        float e2 = a1.x > 0.f ? a1.x : 0.2f*a1.x;
        float e3 = a1.y > 0.f ? a1.y : 0.2f*a1.y;
        __half2 p0 = __floats2half2_rn(e0, e2);
        __half2 p1 = __floats2half2_rn(e1, e3);
        act2_s[c0 + 2*q][l]     = *(unsigned int*)&p0;
        act2_s[c0 + 2*q + 1][l] = *(unsigned int*)&p1;
    }
    __syncthreads();

#pragma unroll
    for (int q = 0; q < 4; q++) { accA[q] = pb2h[(c0 >> 1) + q]; accB[q] = accA[q]; }
#pragma unroll 8
    for (int j = 0; j < 64; j++) {
        unsigned int au = act2_s[j][l];
        __half2 ap = *(__half2*)&au;
        __half2 a0 = __half2half2(__low2half(ap));
        __half2 a1 = __half2half2(__high2half(ap));
        uint4 wq = *reinterpret_cast<const uint4*>(&w2s[j][c0]);
        __half2 w01 = *(__half2*)&wq.x, w23 = *(__half2*)&wq.y;
        __half2 w45 = *(__half2*)&wq.z, w67 = *(__half2*)&wq.w;
        accA[0] = __hfma2(w01, a0, accA[0]); accB[0] = __hfma2(w01, a1, accB[0]);
        accA[1] = __hfma2(w23, a0, accA[1]); accB[1] = __hfma2(w23, a1, accB[1]);
        accA[2] = __hfma2(w45, a0, accA[2]); accB[2] = __hfma2(w45, a1, accB[2]);
        accA[3] = __hfma2(w67, a0, accA[3]); accB[3] = __hfma2(w67, a1, accB[3]);
    }
#pragma unroll
    for (int q = 0; q < 4; q++) {
        float2 a0 = __half22float2(accA[q]);
        float2 a1 = __half22float2(accB[q]);
        int ca = c0 + 2*q, cb2 = ca + 1;
        int ba = base + ca*HWn + px0;
        int bb = base + cb2*HWn + px0;
        unsigned int oua = *reinterpret_cast<const unsigned int*>(outp + ba);
        unsigned int oub = *reinterpret_cast<const unsigned int*>(outp + bb);
        float2 oa = __half22float2(*(__half2*)&oua);
        float2 ob = __half22float2(*(__half2*)&oub);
        float la = lss[ca], lb = lss[cb2];
        *reinterpret_cast<float2*>(out + ba) = make_float2(oa.x + la*a0.x, oa.y + la*a1.x);
        *reinterpret_cast<float2*>(out + bb) = make_float2(ob.x + lb*a0.y, ob.y + lb*a1.y);
    }
}

extern "C" void kernel_launch(void* const* d_in, const int* in_sizes, int n_in,
                              void* d_out, int out_size, void* d_ws, size_t ws_size,
                              hipStream_t stream)
{
    (void)in_sizes; (void)n_in; (void)out_size; (void)ws_size;
    const float* force   = (const float*)d_in[0];
    const float* style   = (const float*)d_in[1];
    const float* illum   = (const float*)d_in[2];
    const float* h_w1    = (const float*)d_in[3];
    const float* h_b1    = (const float*)d_in[4];
    const float* h_w2    = (const float*)d_in[5];
    const float* h_b2    = (const float*)d_in[6];
    const float* h_w3    = (const float*)d_in[7];
    const float* h_b3    = (const float*)d_in[8];
    const float* dw_k    = (const float*)d_in[9];
    const float* pw_w    = (const float*)d_in[10];
    const float* r_dw_k  = (const float*)d_in[11];
    const float* r_dw_b  = (const float*)d_in[12];
    const float* r_pw1_w = (const float*)d_in[13];
    const float* r_pw1_b = (const float*)d_in[14];
    const float* r_pw2_w = (const float*)d_in[15];
    const float* r_pw2_b = (const float*)d_in[16];
    const float* lscale  = (const float*)d_in[17];

    float* out  = (float*)d_out;              // holds GB (half2) until refine overwrites
    float* Xf32 = out + (size_t)NTOT;         // final x fp32
    float* Vf32 = out + 2*(size_t)NTOT;       // final v fp32
    __half2* GB = (__half2*)out;

    char* w = (char*)d_ws;
    __half2* AB = (__half2*)w; w += (size_t)NTOT*4;
    __half*  F  = (__half*)w;  w += (size_t)NTOT*2;
    __half*  XA = (__half*)w;  w += (size_t)NTOT*2;
    __half*  XB = (__half*)w;  w += (size_t)NTOT*2;
    __half*  Vh = (__half*)w;  w += (size_t)NTOT*2;
    float* w1T  = (float*)w;
    float* c1   = w1T + 2048;
    float* pwT  = c1 + 32;
    float* pw1T = pwT + 4096;
    float* pw2T = pw1T + 4096;
    float* mu   = pw2T + 4096;
    float* rs   = mu + 512;
    __half2* w3abP = (__half2*)(rs + 512);
    __half2* w3gbP = w3abP + 2048;
    __half2* b3abP = w3gbP + 2048;
    __half2* b3gbP = b3abP + 64;
    __half* outp = (__half*)AB;               // AB dead after last osc step

    fuseF0<<<NTOT/1024, 256, 0, stream>>>((const float4*)force, (const float4*)illum,
                                          F, XA, Vh);
    prep<<<1, 256, 0, stream>>>(style, h_w1, h_b1, pw_w, r_pw1_w, r_pw2_w, h_w3, h_b3,
                                w1T, c1, pwT, pw1T, pw2T, w3abP, w3gbP, b3abP, b3gbP);
    hyperS<<<dim3(NPIX/256, 2), 256, 0, stream>>>(F, w1T, c1, h_w2, h_b2,
                                                  w3abP, w3gbP, b3abP, b3gbP, AB, GB);
    for (int s = 1; s <= 8; s++) {
        const __half* xin = (s & 1) ? XA : XB;
        __half*      xout = (s & 1) ? XB : XA;
        osc_step<false><<<2048, 256, 0, stream>>>(xin, xout, Vh, F, AB,
                                                  dw_k, pwT, nullptr, nullptr);
    }
    // step 9 (odd): reads XA, writes fp32 x,v directly to d_out
    osc_step<true><<<2048, 256, 0, stream>>>(XA, XB, Vh, F, AB,
                                             dw_k, pwT, Xf32, Vf32);
    inorm_stats<<<Bn*Cn, 256, 0, stream>>>(F, Xf32, mu, rs);
    modulate<<<NTOT/1024, 256, 0, stream>>>(F, (const float4*)Xf32,
                                            (const uint4*)GB, mu, rs, outp);
    refine<<<NPIX/128, 512, 0, stream>>>(outp, r_dw_k, r_dw_b, pw1T, r_pw1_b,
                                         pw2T, r_pw2_b, lscale, out);
}

// Round 14
// 482.363 us; speedup vs baseline: 1.8904x; 1.8904x over previous
//
#include <hip/hip_runtime.h>
#include <hip/hip_fp16.h>

#define Hn 128
#define Wn 128
#define HWn 16384
#define Cn 64
#define Bn 8
#define NTOT (Bn*Cn*HWn)   /* 8388608 */
#define NPIX (Bn*HWn)      /* 131072  */
#define DTc 0.3f
#define EPSc 1e-5f

__device__ __forceinline__ float sigm(float t){ return 1.0f/(1.0f+__expf(-t)); }

// ---------------- F = force + 0.2*illum (fp16) + fused oscillator step 0 ----------------
__global__ void fuseF0(const float4* __restrict__ force, const float4* __restrict__ illum,
                       __half* __restrict__ F, __half* __restrict__ XA, __half* __restrict__ V)
{
    int i = blockIdx.x * blockDim.x + threadIdx.x;      // NTOT/4 threads
    float4 f = force[i], il = illum[i];
    float a0 = f.x + 0.2f*il.x, a1 = f.y + 0.2f*il.y;
    float a2 = f.z + 0.2f*il.z, a3 = f.w + 0.2f*il.w;
    uint2 pf, px, pv;
    __half2 h;
    h = __floats2half2_rn(a0, a1);            pf.x = *(unsigned int*)&h;
    h = __floats2half2_rn(a2, a3);            pf.y = *(unsigned int*)&h;
    h = __floats2half2_rn(0.09f*a0, 0.09f*a1); px.x = *(unsigned int*)&h;
    h = __floats2half2_rn(0.09f*a2, 0.09f*a3); px.y = *(unsigned int*)&h;
    h = __floats2half2_rn(0.3f*a0, 0.3f*a1);   pv.x = *(unsigned int*)&h;
    h = __floats2half2_rn(0.3f*a2, 0.3f*a3);   pv.y = *(unsigned int*)&h;
    *reinterpret_cast<uint2*>(F  + 4*(size_t)i) = pf;
    *reinterpret_cast<uint2*>(XA + 4*(size_t)i) = px;
    *reinterpret_cast<uint2*>(V  + 4*(size_t)i) = pv;
}

// ---------------- prep: style constant + weight transposes + packed w3 pairs ------------
__global__ void prep(const float* __restrict__ style, const float* __restrict__ w1,
                     const float* __restrict__ b1, const float* __restrict__ pw,
                     const float* __restrict__ pw1, const float* __restrict__ pw2,
                     const float* __restrict__ w3, const float* __restrict__ b3,
                     float* __restrict__ w1T, float* __restrict__ c1,
                     float* __restrict__ pwT, float* __restrict__ pw1T,
                     float* __restrict__ pw2T,
                     __half2* __restrict__ w3abP, __half2* __restrict__ w3gbP,
                     __half2* __restrict__ b3abP, __half2* __restrict__ b3gbP)
{
    int t = threadIdx.x;
    if (t < 32) {
        float s = b1[t];
        for (int k = 0; k < 64; k++) s += w1[t*128 + 64 + k] * style[k];
        c1[t] = s;
    }
    for (int i = t; i < 2048; i += 256) { int c = i >> 5, j = i & 31; w1T[i] = w1[j*128 + c]; }
    for (int i = t; i < 4096; i += 256) {
        int c = i >> 6, k = i & 63;
        pwT[i]  = pw[k*64 + c];
        pw1T[i] = pw1[k*64 + c];
        pw2T[i] = pw2[k*64 + c];
    }
    for (int i = t; i < 2048; i += 256) {
        int j = i >> 5, k = i & 31;
        w3abP[i] = __floats2half2_rn(w3[j*32 + k],         w3[(64 + j)*32 + k]);
        w3gbP[i] = __floats2half2_rn(w3[(128 + j)*32 + k], w3[(192 + j)*32 + k]);
    }
    if (t < 64) {
        b3abP[t] = __floats2half2_rn(b3[t],       b3[64 + t]);
        b3gbP[t] = __floats2half2_rn(b3[128 + t], b3[192 + t]);
    }
}

// ---------------- hyper stage 1: u2 per pixel (F staged in LDS) -> U2 fp16 --------------
__global__ __launch_bounds__(256)
void hyperU(const __half* __restrict__ F,
            const float* __restrict__ w1T, const float* __restrict__ c1,
            const float* __restrict__ w2, const float* __restrict__ b2,
            __half* __restrict__ U2)
{
    __shared__ __half fs[64][256];
    int t = threadIdx.x;
    int p0 = blockIdx.x << 8;
    int b  = p0 >> 14;
    int sp0 = p0 & (HWn - 1);
    int tbase = b * Cn * HWn + sp0;

#pragma unroll
    for (int it = 0; it < 8; it++) {
        int f = t + (it << 8);
        int c = f >> 5, u = f & 31;
        uint4 d = *reinterpret_cast<const uint4*>(F + tbase + c*HWn + (u << 3));
        *reinterpret_cast<uint4*>(&fs[c][u << 3]) = d;
    }
    __syncthreads();

    float u1[32];
#pragma unroll
    for (int j = 0; j < 32; j++) u1[j] = c1[j];
#pragma unroll 4
    for (int c = 0; c < 64; c++) {
        float fc = __half2float(fs[c][t]);
        const float* __restrict__ wr = w1T + c*32;
#pragma unroll
        for (int j = 0; j < 32; j++) u1[j] += wr[j] * fc;
    }
#pragma unroll
    for (int j = 0; j < 32; j++) { float v = u1[j]; u1[j] = v > 0.f ? v : 0.2f*v; }

    float u2[32];
#pragma unroll
    for (int i = 0; i < 32; i++) {
        float s = b2[i];
#pragma unroll
        for (int j = 0; j < 32; j++) s += w2[i*32 + j] * u1[j];
        u2[i] = s > 0.f ? s : 0.2f*s;
    }

    uint4* dst = reinterpret_cast<uint4*>(U2 + ((size_t)(p0 + t)) * 32);
#pragma unroll
    for (int q = 0; q < 4; q++) {
        __half2 h0 = __floats2half2_rn(u2[8*q+0], u2[8*q+1]);
        __half2 h1 = __floats2half2_rn(u2[8*q+2], u2[8*q+3]);
        __half2 h2 = __floats2half2_rn(u2[8*q+4], u2[8*q+5]);
        __half2 h3 = __floats2half2_rn(u2[8*q+6], u2[8*q+7]);
        uint4 d;
        d.x = *(unsigned int*)&h0; d.y = *(unsigned int*)&h1;
        d.z = *(unsigned int*)&h2; d.w = *(unsigned int*)&h3;
        dst[q] = d;
    }
}

// ---------------- hyper stage 2: w3 hfma2 -> AB (y=0) / GB (y=1) ----------------
__global__ __launch_bounds__(256)
void hyperW(const __half* __restrict__ U2,
            const __half2* __restrict__ w3abP, const __half2* __restrict__ w3gbP,
            const __half2* __restrict__ b3abP, const __half2* __restrict__ b3gbP,
            __half2* __restrict__ AB, __half2* __restrict__ GB)
{
    int p = blockIdx.x * blockDim.x + threadIdx.x;
    int b  = p >> 14;
    int sp = p & (HWn - 1);
    int base = b * Cn * HWn + sp;

    __half2 u2b[32];
    const uint4* src = reinterpret_cast<const uint4*>(U2 + (size_t)p * 32);
#pragma unroll
    for (int q = 0; q < 4; q++) {
        uint4 d = src[q];
        __half2 h;
        h = *(__half2*)&d.x; u2b[8*q+0] = __half2half2(__low2half(h)); u2b[8*q+1] = __half2half2(__high2half(h));
        h = *(__half2*)&d.y; u2b[8*q+2] = __half2half2(__low2half(h)); u2b[8*q+3] = __half2half2(__high2half(h));
        h = *(__half2*)&d.z; u2b[8*q+4] = __half2half2(__low2half(h)); u2b[8*q+5] = __half2half2(__high2half(h));
        h = *(__half2*)&d.w; u2b[8*q+6] = __half2half2(__low2half(h)); u2b[8*q+7] = __half2half2(__high2half(h));
    }

    if (blockIdx.y == 0) {
#pragma unroll 2
        for (int j = 0; j < 64; j++) {
            __half2 aab = b3abP[j];
            const __half2* __restrict__ wa = w3abP + j*32;
#pragma unroll
            for (int i = 0; i < 32; i++) aab = __hfma2(wa[i], u2b[i], aab);
            float2 tab = __half22float2(aab);
            float om = 2.0f * sigm(tab.x);
            float ze = sigm(tab.y);
            AB[base + j*HWn] = __floats2half2_rn(2.0f * ze * om, om * om);
        }
    } else {
#pragma unroll 2
        for (int j = 0; j < 64; j++) {
            __half2 agb = b3gbP[j];
            const __half2* __restrict__ wg = w3gbP + j*32;
#pragma unroll
            for (int i = 0; i < 32; i++) agb = __hfma2(wg[i], u2b[i], agb);
            float2 tgb = __half22float2(agb);
            GB[base + j*HWn] = __floats2half2_rn(2.0f * sigm(tgb.x), tanhf(tgb.y));
        }
    }
}

// ---------------- one symplectic-Euler oscillator step (R12-proven: R8 + XCD swizzle) ----
template <bool LAST>
__global__ void osc_step(const __half* __restrict__ Xin, __half* __restrict__ Xout,
                         __half* __restrict__ V, const __half* __restrict__ F,
                         const __half2* __restrict__ AB,
                         const float* __restrict__ dwk, const float* __restrict__ pwT,
                         float* __restrict__ Xf, float* __restrict__ Vf)
{
    int wid  = blockIdx.x;
    int slot = wid >> 3;
    int pc   = ((wid & 7) << 6) + (slot >> 2);   // pixel-chunk 0..511
    int c0   = (slot & 3) << 4;                  // channel group start
    int p = (pc << 8) + threadIdx.x;
    int b  = p >> 14;
    int sp = p & (HWn - 1);
    int y = sp >> 7, x = sp & 127;
    int base = b * Cn * HWn + sp;

    float acc[16];
#pragma unroll
    for (int k = 0; k < 16; k++) acc[k] = 0.f;
#pragma unroll 4
    for (int c = 0; c < 64; c++) {
        float xc = __half2float(Xin[base + c*HWn]);
        const float* __restrict__ wr = pwT + c*64 + c0;
#pragma unroll
        for (int k = 0; k < 16; k++) acc[k] += wr[k] * xc;
    }

    int   yo[3] = { y > 0 ? -Wn : 0, 0, y < Hn-1 ? Wn : 0 };
    int   xo[3] = { x > 0 ? -1  : 0, 0, x < Wn-1 ? 1  : 0 };
    float my[3] = { y > 0 ? 1.f : 0.f, 1.f, y < Hn-1 ? 1.f : 0.f };
    float mx[3] = { x > 0 ? 1.f : 0.f, 1.f, x < Wn-1 ? 1.f : 0.f };
    float mm[9]; int oo[9];
#pragma unroll
    for (int dy = 0; dy < 3; dy++)
#pragma unroll
        for (int dx = 0; dx < 3; dx++) { mm[dy*3+dx] = my[dy]*mx[dx]; oo[dy*3+dx] = yo[dy]+xo[dx]; }

#pragma unroll
    for (int cc = 0; cc < 16; cc++) {
        int c = c0 + cc;
        int cb = base + c*HWn;
        float tv[9];
#pragma unroll
        for (int t = 0; t < 9; t++) tv[t] = __half2float(Xin[cb + oo[t]]);
        float dws = 0.f;
#pragma unroll
        for (int t = 0; t < 9; t++) dws += (dwk[c*9 + t] * mm[t]) * tv[t];
        float xc = tv[4];
        float2 ab = __half22float2(AB[cb]);
        float vv = __half2float(V[cb]);
        float accel = __half2float(F[cb]) + acc[cc] + dws - ab.x * vv - ab.y * xc;
        vv += accel * DTc;
        float xn = xc + vv * DTc;
        if constexpr (!LAST) {
            V[cb] = __float2half(vv);
            Xout[cb] = __float2half(xn);
        } else {
            Xf[cb] = xn;
            Vf[cb] = vv;
        }
    }
}

// ---------------- instance norm stats ----------------
__global__ void inorm_stats(const __half* __restrict__ F, const float* __restrict__ X,
                            float* __restrict__ mu, float* __restrict__ rs)
{
    int bc = blockIdx.x;             // 0..511
    int base = bc * HWn;
    const __half2* __restrict__ F2 = (const __half2*)(F + base);
    const float4*  __restrict__ X4 = (const float4*)(X + base);
    float s = 0.f, s2 = 0.f;
    for (int i = threadIdx.x; i < HWn/4; i += blockDim.x) {
        float4 xv = X4[i];
        float2 f0 = __half22float2(F2[2*i]);
        float2 f1 = __half22float2(F2[2*i+1]);
        float v0 = f0.x + xv.x, v1 = f0.y + xv.y, v2 = f1.x + xv.z, v3 = f1.y + xv.w;
        s += (v0 + v1) + (v2 + v3);
        s2 += (v0*v0 + v1*v1) + (v2*v2 + v3*v3);
    }
#pragma unroll
    for (int o = 32; o > 0; o >>= 1) { s += __shfl_down(s, o); s2 += __shfl_down(s2, o); }
    __shared__ float sh[16];
    int w = threadIdx.x >> 6, l = threadIdx.x & 63;
    if (l == 0) { sh[w] = s; sh[8 + w] = s2; }
    __syncthreads();
    if (threadIdx.x == 0) {
        float S = 0.f, S2 = 0.f;
        for (int i = 0; i < 4; i++) { S += sh[i]; S2 += sh[8 + i]; }
        float m = S / (float)HWn;
        float var = S2 / (float)HWn - m*m;
        mu[bc] = m;
        rs[bc] = rsqrtf(var + EPSc);
    }
}

// ---------------- instance norm apply + style modulation -> out_pre (fp16) ----------------
__global__ void modulate(const __half* __restrict__ F, const float4* __restrict__ X4,
                         const uint4* __restrict__ GBu, const float* __restrict__ mu,
                         const float* __restrict__ rs, __half* __restrict__ outp)
{
    int e4 = blockIdx.x * blockDim.x + threadIdx.x;   // NTOT/4 threads
    int bc = e4 >> 12;                                // (e4*4) >> 14
    float m = mu[bc], r = rs[bc];
    uint2 fu = *reinterpret_cast<const uint2*>(F + 4*(size_t)e4);
    float2 f0 = __half22float2(*(__half2*)&fu.x);
    float2 f1 = __half22float2(*(__half2*)&fu.y);
    float4 xv = X4[e4];
    uint4 gb = GBu[e4];
    float2 g0 = __half22float2(*(__half2*)&gb.x);
    float2 g1 = __half22float2(*(__half2*)&gb.y);
    float2 g2 = __half22float2(*(__half2*)&gb.z);
    float2 g3 = __half22float2(*(__half2*)&gb.w);
    float o0 = g0.x * ((f0.x + xv.x - m) * r) + g0.y;
    float o1 = g1.x * ((f0.y + xv.y - m) * r) + g1.y;
    float o2 = g2.x * ((f1.x + xv.z - m) * r) + g2.y;
    float o3 = g3.x * ((f1.y + xv.w - m) * r) + g3.y;
    __half2 h01 = __floats2half2_rn(o0, o1);
    __half2 h23 = __floats2half2_rn(o2, o3);
    uint2 pack; pack.x = *(unsigned int*)&h01; pack.y = *(unsigned int*)&h23;
    *reinterpret_cast<uint2*>(outp + 4*(size_t)e4) = pack;
}

// ---------------- refine v3: one row/block, 2 px x 8 ch per thread, b128 weight reads ----
__global__ __launch_bounds__(512)
void refine(const __half* __restrict__ outp,
            const float* __restrict__ rdwk, const float* __restrict__ rdwb,
            const float* __restrict__ pw1T, const float* __restrict__ pb1,
            const float* __restrict__ pw2T, const float* __restrict__ pb2,
            const float* __restrict__ ls, float* __restrict__ out)
{
    __shared__ unsigned int rv2_s[64][64];
    __shared__ unsigned int act2_s[64][64];
    __shared__ __half w1s[64][64];
    __shared__ __half w2s[64][64];
    __shared__ float  dwks[576];
    __shared__ __half2 pb1h[32], pb2h[32];
    __shared__ float  rdwbs[64], lss[64];
    int t = threadIdx.x;
    for (int i = t; i < 4096; i += 512) {
        w1s[i>>6][i&63] = __float2half(pw1T[i]);
        w2s[i>>6][i&63] = __float2half(pw2T[i]);
    }
    for (int i = t; i < 576; i += 512) dwks[i] = rdwk[i];
    if (t < 64) { rdwbs[t]=rdwb[t]; lss[t]=ls[t]; }
    if (t < 32) {
        pb1h[t] = __floats2half2_rn(pb1[2*t], pb1[2*t+1]);
        pb2h[t] = __floats2half2_rn(pb2[2*t], pb2[2*t+1]);
    }

    int l  = t & 63;
    int g  = t >> 6;
    int c0 = g << 3;
    int row = blockIdx.x;
    int b = row >> 7, y = row & 127;
    int base = b * Cn * HWn + y * Wn;
    int px0 = l << 1;

    int   yo[3] = { y > 0 ? -Wn : 0, 0, y < Hn-1 ? Wn : 0 };
    float my[3] = { y > 0 ? 1.f : 0.f, 1.f, y < Hn-1 ? 1.f : 0.f };
    float wl = l > 0  ? 1.f : 0.f;
    float wr = l < 63 ? 1.f : 0.f;
    int loff = l > 0 ? -1 : 0;
    __syncthreads();

#pragma unroll
    for (int cc = 0; cc < 8; cc++) {
        int c = c0 + cc;
        int cb = base + c*HWn + px0;
        float rv0 = rdwbs[c], rv1 = rdwbs[c];
#pragma unroll
        for (int r = 0; r < 3; r++) {
            const __half* __restrict__ rp = outp + cb + yo[r];
            unsigned int cu = *reinterpret_cast<const unsigned int*>(rp);
            float2 ct = __half22float2(*(__half2*)&cu);
            float lf = __half2float(rp[loff]);
            float rt = __half2float(rp[2]);
            float k0 = dwks[c*9 + r*3 + 0] * my[r];
            float k1 = dwks[c*9 + r*3 + 1] * my[r];
            float k2 = dwks[c*9 + r*3 + 2] * my[r];
            rv0 += k0*(wl*lf) + k1*ct.x + k2*ct.y;
            rv1 += k0*ct.x + k1*ct.y + k2*(wr*rt);
        }
        __half2 hv = __floats2half2_rn(rv0, rv1);
        rv2_s[c][l] = *(unsigned int*)&hv;
    }
    __syncthreads();

    __half2 accA[4], accB[4];
#pragma unroll
    for (int q = 0; q < 4; q++) { accA[q] = pb1h[(c0 >> 1) + q]; accB[q] = accA[q]; }
#pragma unroll 8
    for (int c = 0; c < 64; c++) {
        unsigned int rvu = rv2_s[c][l];
        __half2 rvp = *(__half2*)&rvu;
        __half2 r0 = __half2half2(__low2half(rvp));
        __half2 r1 = __half2half2(__high2half(rvp));
        uint4 wq = *reinterpret_cast<const uint4*>(&w1s[c][c0]);
        __half2 w01 = *(__half2*)&wq.x, w23 = *(__half2*)&wq.y;
        __half2 w45 = *(__half2*)&wq.z, w67 = *(__half2*)&wq.w;
        accA[0] = __hfma2(w01, r0, accA[0]); accB[0] = __hfma2(w01, r1, accB[0]);
        accA[1] = __hfma2(w23, r0, accA[1]); accB[1] = __hfma2(w23, r1, accB[1]);
        accA[2] = __hfma2(w45, r0, accA[2]); accB[2] = __hfma2(w45, r1, accB[2]);
        accA[3] = __hfma2(w67, r0, accA[3]); accB[3] = __hfma2(w67, r1, accB[3]);
    }
#pragma unroll
    for (int q = 0; q < 4; q++) {
        float2 a0 = __half22float2(accA[q]);
        float2 a1 = __half22float2(accB[q]);
        float e0 = a0.x > 0.f ? a0.x : 0.2f*a0.x;
        float e1 = a0.y > 0.f ? a0.y : 0.2f*a0.y;
        float e2 = a1.x > 0.f ? a1.x : 0.2f*a1.x;
        float e3 = a1.y > 0.f ? a1.y : 0.2f*a1.y;
        __half2 p0 = __floats2half2_rn(e0, e2);
        __half2 p1 = __floats2half2_rn(e1, e3);
        act2_s[c0 + 2*q][l]     = *(unsigned int*)&p0;
        act2_s[c0 + 2*q + 1][l] = *(unsigned int*)&p1;
    }
    __syncthreads();

#pragma unroll
    for (int q = 0; q < 4; q++) { accA[q] = pb2h[(c0 >> 1) + q]; accB[q] = accA[q]; }
#pragma unroll 8
    for (int j = 0; j < 64; j++) {
        unsigned int au = act2_s[j][l];
        __half2 ap = *(__half2*)&au;
        __half2 a0 = __half2half2(__low2half(ap));
        __half2 a1 = __half2half2(__high2half(ap));
        uint4 wq = *reinterpret_cast<const uint4*>(&w2s[j][c0]);
        __half2 w01 = *(__half2*)&wq.x, w23 = *(__half2*)&wq.y;
        __half2 w45 = *(__half2*)&wq.z, w67 = *(__half2*)&wq.w;
        accA[0] = __hfma2(w01, a0, accA[0]); accB[0] = __hfma2(w01, a1, accB[0]);
        accA[1] = __hfma2(w23, a0, accA[1]); accB[1] = __hfma2(w23, a1, accB[1]);
        accA[2] = __hfma2(w45, a0, accA[2]); accB[2] = __hfma2(w45, a1, accB[2]);
        accA[3] = __hfma2(w67, a0, accA[3]); accB[3] = __hfma2(w67, a1, accB[3]);
    }
#pragma unroll
    for (int q = 0; q < 4; q++) {
        float2 a0 = __half22float2(accA[q]);
        float2 a1 = __half22float2(accB[q]);
        int ca = c0 + 2*q, cb2 = ca + 1;
        int ba = base + ca*HWn + px0;
        int bb = base + cb2*HWn + px0;
        unsigned int oua = *reinterpret_cast<const unsigned int*>(outp + ba);
        unsigned int oub = *reinterpret_cast<const unsigned int*>(outp + bb);
        float2 oa = __half22float2(*(__half2*)&oua);
        float2 ob = __half22float2(*(__half2*)&oub);
        float la = lss[ca], lb = lss[cb2];
        *reinterpret_cast<float2*>(out + ba) = make_float2(oa.x + la*a0.x, oa.y + la*a1.x);
        *reinterpret_cast<float2*>(out + bb) = make_float2(ob.x + lb*a0.y, ob.y + lb*a1.y);
    }
}

extern "C" void kernel_launch(void* const* d_in, const int* in_sizes, int n_in,
                              void* d_out, int out_size, void* d_ws, size_t ws_size,
                              hipStream_t stream)
{
    (void)in_sizes; (void)n_in; (void)out_size; (void)ws_size;
    const float* force   = (const float*)d_in[0];
    const float* style   = (const float*)d_in[1];
    const float* illum   = (const float*)d_in[2];
    const float* h_w1    = (const float*)d_in[3];
    const float* h_b1    = (const float*)d_in[4];
    const float* h_w2    = (const float*)d_in[5];
    const float* h_b2    = (const float*)d_in[6];
    const float* h_w3    = (const float*)d_in[7];
    const float* h_b3    = (const float*)d_in[8];
    const float* dw_k    = (const float*)d_in[9];
    const float* pw_w    = (const float*)d_in[10];
    const float* r_dw_k  = (const float*)d_in[11];
    const float* r_dw_b  = (const float*)d_in[12];
    const float* r_pw1_w = (const float*)d_in[13];
    const float* r_pw1_b = (const float*)d_in[14];
    const float* r_pw2_w = (const float*)d_in[15];
    const float* r_pw2_b = (const float*)d_in[16];
    const float* lscale  = (const float*)d_in[17];

    float* out  = (float*)d_out;              // holds GB (half2) until refine overwrites
    float* Xf32 = out + (size_t)NTOT;         // final x fp32 (U2 parks here pre-osc)
    float* Vf32 = out + 2*(size_t)NTOT;       // final v fp32
    __half2* GB = (__half2*)out;
    __half*  U2h = (__half*)Xf32;             // 8.4 MB, dead after hyperW

    char* w = (char*)d_ws;
    __half2* AB = (__half2*)w; w += (size_t)NTOT*4;
    __half*  F  = (__half*)w;  w += (size_t)NTOT*2;
    __half*  XA = (__half*)w;  w += (size_t)NTOT*2;
    __half*  XB = (__half*)w;  w += (size_t)NTOT*2;
    __half*  Vh = (__half*)w;  w += (size_t)NTOT*2;
    float* w1T  = (float*)w;
    float* c1   = w1T + 2048;
    float* pwT  = c1 + 32;
    float* pw1T = pwT + 4096;
    float* pw2T = pw1T + 4096;
    float* mu   = pw2T + 4096;
    float* rs   = mu + 512;
    __half2* w3abP = (__half2*)(rs + 512);
    __half2* w3gbP = w3abP + 2048;
    __half2* b3abP = w3gbP + 2048;
    __half2* b3gbP = b3abP + 64;
    __half* outp = (__half*)AB;               // AB dead after last osc step

    fuseF0<<<NTOT/1024, 256, 0, stream>>>((const float4*)force, (const float4*)illum,
                                          F, XA, Vh);
    prep<<<1, 256, 0, stream>>>(style, h_w1, h_b1, pw_w, r_pw1_w, r_pw2_w, h_w3, h_b3,
                                w1T, c1, pwT, pw1T, pw2T, w3abP, w3gbP, b3abP, b3gbP);
    hyperU<<<NPIX/256, 256, 0, stream>>>(F, w1T, c1, h_w2, h_b2, U2h);
    hyperW<<<dim3(NPIX/256, 2), 256, 0, stream>>>(U2h, w3abP, w3gbP, b3abP, b3gbP, AB, GB);
    for (int s = 1; s <= 8; s++) {
        const __half* xin = (s & 1) ? XA : XB;
        __half*      xout = (s & 1) ? XB : XA;
        osc_step<false><<<2048, 256, 0, stream>>>(xin, xout, Vh, F, AB,
                                                  dw_k, pwT, nullptr, nullptr);
    }
    // step 9 (odd): reads XA, writes fp32 x,v directly to d_out (overwrites dead U2)
    osc_step<true><<<2048, 256, 0, stream>>>(XA, XB, Vh, F, AB,
                                             dw_k, pwT, Xf32, Vf32);
    inorm_stats<<<Bn*Cn, 256, 0, stream>>>(F, Xf32, mu, rs);
    modulate<<<NTOT/1024, 256, 0, stream>>>(F, (const float4*)Xf32,
                                            (const uint4*)GB, mu, rs, outp);
    refine<<<NPIX/128, 512, 0, stream>>>(outp, r_dw_k, r_dw_b, pw1T, r_pw1_b,
                                         pw2T, r_pw2_b, lscale, out);
}

// Round 15
// 453.585 us; speedup vs baseline: 2.0104x; 1.0634x over previous
//
#include <hip/hip_runtime.h>
#include <hip/hip_fp16.h>

#define Hn 128
#define Wn 128
#define HWn 16384
#define Cn 64
#define Bn 8
#define NTOT (Bn*Cn*HWn)   /* 8388608 */
#define NPIX (Bn*HWn)      /* 131072  */
#define DTc 0.3f
#define EPSc 1e-5f

__device__ __forceinline__ float sigm(float t){ return 1.0f/(1.0f+__expf(-t)); }

// ---------------- prep: style constant + weight transposes + packed w3 pairs ------------
__global__ void prep(const float* __restrict__ style, const float* __restrict__ w1,
                     const float* __restrict__ b1, const float* __restrict__ pw,
                     const float* __restrict__ pw1, const float* __restrict__ pw2,
                     const float* __restrict__ w3, const float* __restrict__ b3,
                     float* __restrict__ w1T, float* __restrict__ c1,
                     float* __restrict__ pwT, float* __restrict__ pw1T,
                     float* __restrict__ pw2T,
                     __half2* __restrict__ w3abP, __half2* __restrict__ w3gbP,
                     __half2* __restrict__ b3abP, __half2* __restrict__ b3gbP)
{
    int t = threadIdx.x;
    if (t < 32) {
        float s = b1[t];
        for (int k = 0; k < 64; k++) s += w1[t*128 + 64 + k] * style[k];
        c1[t] = s;
    }
    for (int i = t; i < 2048; i += 256) { int c = i >> 5, j = i & 31; w1T[i] = w1[j*128 + c]; }
    for (int i = t; i < 4096; i += 256) {
        int c = i >> 6, k = i & 63;
        pwT[i]  = pw[k*64 + c];
        pw1T[i] = pw1[k*64 + c];
        pw2T[i] = pw2[k*64 + c];
    }
    for (int i = t; i < 2048; i += 256) {
        int j = i >> 5, k = i & 31;
        w3abP[i] = __floats2half2_rn(w3[j*32 + k],         w3[(64 + j)*32 + k]);
        w3gbP[i] = __floats2half2_rn(w3[(128 + j)*32 + k], w3[(192 + j)*32 + k]);
    }
    if (t < 64) {
        b3abP[t] = __floats2half2_rn(b3[t],       b3[64 + t]);
        b3gbP[t] = __floats2half2_rn(b3[128 + t], b3[192 + t]);
    }
}

// ---------------- hyper stage 1 + fused F/XA/V producer ----------------
// Computes F = force + 0.2*illum into LDS tile, writes F / XA=0.09F / Vh=0.3F (step-0
// closed form), then u1 -> u2 per pixel -> U2 fp16.
__global__ __launch_bounds__(256)
void hyperU(const float4* __restrict__ force4, const float4* __restrict__ illum4,
            const float* __restrict__ w1T, const float* __restrict__ c1,
            const float* __restrict__ w2, const float* __restrict__ b2,
            __half* __restrict__ F, __half* __restrict__ XA, __half* __restrict__ Vh,
            __half* __restrict__ U2)
{
    __shared__ __half fs[64][256];
    int t = threadIdx.x;
    int p0 = blockIdx.x << 8;
    int b  = p0 >> 14;
    int sp0 = p0 & (HWn - 1);
    size_t tbase = (size_t)b * Cn * HWn + sp0;      // element idx, multiple of 256
    size_t tb4   = tbase >> 2;                      // float4 idx

    // stage F tile from force/illum: 4096 float4-pairs, 16 per thread, coalesced
#pragma unroll
    for (int it = 0; it < 16; it++) {
        int f = t + (it << 8);          // 0..4095
        int c = f >> 6, u = f & 63;     // 64 float4 per channel row
        size_t gi = tb4 + (size_t)c * (HWn >> 2) + u;
        float4 fv = force4[gi], iv = illum4[gi];
        __half2 h0 = __floats2half2_rn(fv.x + 0.2f*iv.x, fv.y + 0.2f*iv.y);
        __half2 h1 = __floats2half2_rn(fv.z + 0.2f*iv.z, fv.w + 0.2f*iv.w);
        uint2 pk; pk.x = *(unsigned int*)&h0; pk.y = *(unsigned int*)&h1;
        *reinterpret_cast<uint2*>(&fs[c][u << 2]) = pk;
    }
    __syncthreads();

    // write back F, XA = 0.09F, Vh = 0.3F: 2048 uint4, 8 per thread
#pragma unroll
    for (int it = 0; it < 8; it++) {
        int f = t + (it << 8);
        int c = f >> 5, u = f & 31;
        uint4 d = *reinterpret_cast<const uint4*>(&fs[c][u << 3]);
        size_t gi = tbase + (size_t)c * HWn + (u << 3);
        *reinterpret_cast<uint4*>(F + gi) = d;
        uint4 xk, vk;
        unsigned int* dp = &d.x;
        unsigned int* xp = &xk.x;
        unsigned int* vp = &vk.x;
#pragma unroll
        for (int q = 0; q < 4; q++) {
            float2 fv = __half22float2(*(__half2*)&dp[q]);
            __half2 hx = __floats2half2_rn(0.09f*fv.x, 0.09f*fv.y);
            __half2 hv = __floats2half2_rn(0.3f*fv.x,  0.3f*fv.y);
            xp[q] = *(unsigned int*)&hx;
            vp[q] = *(unsigned int*)&hv;
        }
        *reinterpret_cast<uint4*>(XA + gi) = xk;
        *reinterpret_cast<uint4*>(Vh + gi) = vk;
    }

    float u1[32];
#pragma unroll
    for (int j = 0; j < 32; j++) u1[j] = c1[j];
#pragma unroll 4
    for (int c = 0; c < 64; c++) {
        float fc = __half2float(fs[c][t]);
        const float* __restrict__ wr = w1T + c*32;
#pragma unroll
        for (int j = 0; j < 32; j++) u1[j] += wr[j] * fc;
    }
#pragma unroll
    for (int j = 0; j < 32; j++) { float v = u1[j]; u1[j] = v > 0.f ? v : 0.2f*v; }

    float u2[32];
#pragma unroll
    for (int i = 0; i < 32; i++) {
        float s = b2[i];
#pragma unroll
        for (int j = 0; j < 32; j++) s += w2[i*32 + j] * u1[j];
        u2[i] = s > 0.f ? s : 0.2f*s;
    }

    uint4* dst = reinterpret_cast<uint4*>(U2 + ((size_t)(p0 + t)) * 32);
#pragma unroll
    for (int q = 0; q < 4; q++) {
        __half2 h0 = __floats2half2_rn(u2[8*q+0], u2[8*q+1]);
        __half2 h1 = __floats2half2_rn(u2[8*q+2], u2[8*q+3]);
        __half2 h2 = __floats2half2_rn(u2[8*q+4], u2[8*q+5]);
        __half2 h3 = __floats2half2_rn(u2[8*q+6], u2[8*q+7]);
        uint4 d;
        d.x = *(unsigned int*)&h0; d.y = *(unsigned int*)&h1;
        d.z = *(unsigned int*)&h2; d.w = *(unsigned int*)&h3;
        dst[q] = d;
    }
}

// ---------------- hyper stage 2: AB only, j-split x2 ----------------
__global__ __launch_bounds__(256)
void hyperA(const __half* __restrict__ U2,
            const __half2* __restrict__ w3abP, const __half2* __restrict__ b3abP,
            __half2* __restrict__ AB)
{
    int p = blockIdx.x * blockDim.x + threadIdx.x;
    int j0 = blockIdx.y << 5;                     // 0 or 32
    int b  = p >> 14;
    int sp = p & (HWn - 1);
    int base = b * Cn * HWn + sp;

    __half2 u2b[32];
    const uint4* src = reinterpret_cast<const uint4*>(U2 + (size_t)p * 32);
#pragma unroll
    for (int q = 0; q < 4; q++) {
        uint4 d = src[q];
        __half2 h;
        h = *(__half2*)&d.x; u2b[8*q+0] = __half2half2(__low2half(h)); u2b[8*q+1] = __half2half2(__high2half(h));
        h = *(__half2*)&d.y; u2b[8*q+2] = __half2half2(__low2half(h)); u2b[8*q+3] = __half2half2(__high2half(h));
        h = *(__half2*)&d.z; u2b[8*q+4] = __half2half2(__low2half(h)); u2b[8*q+5] = __half2half2(__high2half(h));
        h = *(__half2*)&d.w; u2b[8*q+6] = __half2half2(__low2half(h)); u2b[8*q+7] = __half2half2(__high2half(h));
    }

#pragma unroll 2
    for (int jj = 0; jj < 32; jj++) {
        int j = j0 + jj;
        __half2 aab = b3abP[j];
        const __half2* __restrict__ wa = w3abP + j*32;
#pragma unroll
        for (int i = 0; i < 32; i++) aab = __hfma2(wa[i], u2b[i], aab);
        float2 tab = __half22float2(aab);
        float om = 2.0f * sigm(tab.x);
        float ze = sigm(tab.y);
        AB[base + j*HWn] = __floats2half2_rn(2.0f * ze * om, om * om);
    }
}

// ---------------- one symplectic-Euler oscillator step (R12-proven, FROZEN) ------------
template <bool LAST>
__global__ void osc_step(const __half* __restrict__ Xin, __half* __restrict__ Xout,
                         __half* __restrict__ V, const __half* __restrict__ F,
                         const __half2* __restrict__ AB,
                         const float* __restrict__ dwk, const float* __restrict__ pwT,
                         float* __restrict__ Xf, float* __restrict__ Vf)
{
    int wid  = blockIdx.x;
    int slot = wid >> 3;
    int pc   = ((wid & 7) << 6) + (slot >> 2);   // pixel-chunk 0..511
    int c0   = (slot & 3) << 4;                  // channel group start
    int p = (pc << 8) + threadIdx.x;
    int b  = p >> 14;
    int sp = p & (HWn - 1);
    int y = sp >> 7, x = sp & 127;
    int base = b * Cn * HWn + sp;

    float acc[16];
#pragma unroll
    for (int k = 0; k < 16; k++) acc[k] = 0.f;
#pragma unroll 4
    for (int c = 0; c < 64; c++) {
        float xc = __half2float(Xin[base + c*HWn]);
        const float* __restrict__ wr = pwT + c*64 + c0;
#pragma unroll
        for (int k = 0; k < 16; k++) acc[k] += wr[k] * xc;
    }

    int   yo[3] = { y > 0 ? -Wn : 0, 0, y < Hn-1 ? Wn : 0 };
    int   xo[3] = { x > 0 ? -1  : 0, 0, x < Wn-1 ? 1  : 0 };
    float my[3] = { y > 0 ? 1.f : 0.f, 1.f, y < Hn-1 ? 1.f : 0.f };
    float mx[3] = { x > 0 ? 1.f : 0.f, 1.f, x < Wn-1 ? 1.f : 0.f };
    float mm[9]; int oo[9];
#pragma unroll
    for (int dy = 0; dy < 3; dy++)
#pragma unroll
        for (int dx = 0; dx < 3; dx++) { mm[dy*3+dx] = my[dy]*mx[dx]; oo[dy*3+dx] = yo[dy]+xo[dx]; }

#pragma unroll
    for (int cc = 0; cc < 16; cc++) {
        int c = c0 + cc;
        int cb = base + c*HWn;
        float tv[9];
#pragma unroll
        for (int t = 0; t < 9; t++) tv[t] = __half2float(Xin[cb + oo[t]]);
        float dws = 0.f;
#pragma unroll
        for (int t = 0; t < 9; t++) dws += (dwk[c*9 + t] * mm[t]) * tv[t];
        float xc = tv[4];
        float2 ab = __half22float2(AB[cb]);
        float vv = __half2float(V[cb]);
        float accel = __half2float(F[cb]) + acc[cc] + dws - ab.x * vv - ab.y * xc;
        vv += accel * DTc;
        float xn = xc + vv * DTc;
        if constexpr (!LAST) {
            V[cb] = __float2half(vv);
            Xout[cb] = __float2half(xn);
        } else {
            Xf[cb] = xn;
            Vf[cb] = vv;
        }
    }
}

// ---------------- instance norm stats ----------------
__global__ void inorm_stats(const __half* __restrict__ F, const float* __restrict__ X,
                            float* __restrict__ mu, float* __restrict__ rs)
{
    int bc = blockIdx.x;             // 0..511
    int base = bc * HWn;
    const __half2* __restrict__ F2 = (const __half2*)(F + base);
    const float4*  __restrict__ X4 = (const float4*)(X + base);
    float s = 0.f, s2 = 0.f;
    for (int i = threadIdx.x; i < HWn/4; i += blockDim.x) {
        float4 xv = X4[i];
        float2 f0 = __half22float2(F2[2*i]);
        float2 f1 = __half22float2(F2[2*i+1]);
        float v0 = f0.x + xv.x, v1 = f0.y + xv.y, v2 = f1.x + xv.z, v3 = f1.y + xv.w;
        s += (v0 + v1) + (v2 + v3);
        s2 += (v0*v0 + v1*v1) + (v2*v2 + v3*v3);
    }
#pragma unroll
    for (int o = 32; o > 0; o >>= 1) { s += __shfl_down(s, o); s2 += __shfl_down(s2, o); }
    __shared__ float sh[16];
    int w = threadIdx.x >> 6, l = threadIdx.x & 63;
    if (l == 0) { sh[w] = s; sh[8 + w] = s2; }
    __syncthreads();
    if (threadIdx.x == 0) {
        float S = 0.f, S2 = 0.f;
        for (int i = 0; i < 4; i++) { S += sh[i]; S2 += sh[8 + i]; }
        float m = S / (float)HWn;
        float var = S2 / (float)HWn - m*m;
        mu[bc] = m;
        rs[bc] = rsqrtf(var + EPSc);
    }
}

// ---------------- fused gamma/beta + instance-norm modulation -> outp (fp16) ------------
// grid (512, 4): j-split x4 for occupancy. gamma/beta recomputed from U2 (kills GB buffer).
__global__ __launch_bounds__(256)
void modGB(const __half* __restrict__ U2, const __half* __restrict__ F,
           const float* __restrict__ X,
           const __half2* __restrict__ w3gbP, const __half2* __restrict__ b3gbP,
           const float* __restrict__ mu, const float* __restrict__ rs,
           __half* __restrict__ outp)
{
    int p = blockIdx.x * blockDim.x + threadIdx.x;
    int j0 = blockIdx.y << 4;                     // 0,16,32,48
    int b  = p >> 14;
    int sp = p & (HWn - 1);
    int base = b * Cn * HWn + sp;

    __half2 u2b[32];
    const uint4* src = reinterpret_cast<const uint4*>(U2 + (size_t)p * 32);
#pragma unroll
    for (int q = 0; q < 4; q++) {
        uint4 d = src[q];
        __half2 h;
        h = *(__half2*)&d.x; u2b[8*q+0] = __half2half2(__low2half(h)); u2b[8*q+1] = __half2half2(__high2half(h));
        h = *(__half2*)&d.y; u2b[8*q+2] = __half2half2(__low2half(h)); u2b[8*q+3] = __half2half2(__high2half(h));
        h = *(__half2*)&d.z; u2b[8*q+4] = __half2half2(__low2half(h)); u2b[8*q+5] = __half2half2(__high2half(h));
        h = *(__half2*)&d.w; u2b[8*q+6] = __half2half2(__low2half(h)); u2b[8*q+7] = __half2half2(__high2half(h));
    }

#pragma unroll 2
    for (int jj = 0; jj < 16; jj++) {
        int j = j0 + jj;
        __half2 agb = b3gbP[j];
        const __half2* __restrict__ wg = w3gbP + j*32;
#pragma unroll
        for (int i = 0; i < 32; i++) agb = __hfma2(wg[i], u2b[i], agb);
        float2 tgb = __half22float2(agb);
        float gamma = 2.0f * sigm(tgb.x);
        float beta  = tanhf(tgb.y);
        int cb = base + j*HWn;
        int bc = b*64 + j;
        float fx = __half2float(F[cb]) + X[cb];
        float o = gamma * ((fx - mu[bc]) * rs[bc]) + beta;
        outp[cb] = __float2half(o);
    }
}

// ---------------- refine v3 (FROZEN): one row/block, 2 px x 8 ch, b128 weight reads -----
__global__ __launch_bounds__(512)
void refine(const __half* __restrict__ outp,
            const float* __restrict__ rdwk, const float* __restrict__ rdwb,
            const float* __restrict__ pw1T, const float* __restrict__ pb1,
            const float* __restrict__ pw2T, const float* __restrict__ pb2,
            const float* __restrict__ ls, float* __restrict__ out)
{
    __shared__ unsigned int rv2_s[64][64];
    __shared__ unsigned int act2_s[64][64];
    __shared__ __half w1s[64][64];
    __shared__ __half w2s[64][64];
    __shared__ float  dwks[576];
    __shared__ __half2 pb1h[32], pb2h[32];
    __shared__ float  rdwbs[64], lss[64];
    int t = threadIdx.x;
    for (int i = t; i < 4096; i += 512) {
        w1s[i>>6][i&63] = __float2half(pw1T[i]);
        w2s[i>>6][i&63] = __float2half(pw2T[i]);
    }
    for (int i = t; i < 576; i += 512) dwks[i] = rdwk[i];
    if (t < 64) { rdwbs[t]=rdwb[t]; lss[t]=ls[t]; }
    if (t < 32) {
        pb1h[t] = __floats2half2_rn(pb1[2*t], pb1[2*t+1]);
        pb2h[t] = __floats2half2_rn(pb2[2*t], pb2[2*t+1]);
    }

    int l  = t & 63;
    int g  = t >> 6;
    int c0 = g << 3;
    int row = blockIdx.x;
    int b = row >> 7, y = row & 127;
    int base = b * Cn * HWn + y * Wn;
    int px0 = l << 1;

    int   yo[3] = { y > 0 ? -Wn : 0, 0, y < Hn-1 ? Wn : 0 };
    float my[3] = { y > 0 ? 1.f : 0.f, 1.f, y < Hn-1 ? 1.f : 0.f };
    float wl = l > 0  ? 1.f : 0.f;
    float wr = l < 63 ? 1.f : 0.f;
    int loff = l > 0 ? -1 : 0;
    __syncthreads();

#pragma unroll
    for (int cc = 0; cc < 8; cc++) {
        int c = c0 + cc;
        int cb = base + c*HWn + px0;
        float rv0 = rdwbs[c], rv1 = rdwbs[c];
#pragma unroll
        for (int r = 0; r < 3; r++) {
            const __half* __restrict__ rp = outp + cb + yo[r];
            unsigned int cu = *reinterpret_cast<const unsigned int*>(rp);
            float2 ct = __half22float2(*(__half2*)&cu);
            float lf = __half2float(rp[loff]);
            float rt = __half2float(rp[2]);
            float k0 = dwks[c*9 + r*3 + 0] * my[r];
            float k1 = dwks[c*9 + r*3 + 1] * my[r];
            float k2 = dwks[c*9 + r*3 + 2] * my[r];
            rv0 += k0*(wl*lf) + k1*ct.x + k2*ct.y;
            rv1 += k0*ct.x + k1*ct.y + k2*(wr*rt);
        }
        __half2 hv = __floats2half2_rn(rv0, rv1);
        rv2_s[c][l] = *(unsigned int*)&hv;
    }
    __syncthreads();

    __half2 accA[4], accB[4];
#pragma unroll
    for (int q = 0; q < 4; q++) { accA[q] = pb1h[(c0 >> 1) + q]; accB[q] = accA[q]; }
#pragma unroll 8
    for (int c = 0; c < 64; c++) {
        unsigned int rvu = rv2_s[c][l];
        __half2 rvp = *(__half2*)&rvu;
        __half2 r0 = __half2half2(__low2half(rvp));
        __half2 r1 = __half2half2(__high2half(rvp));
        uint4 wq = *reinterpret_cast<const uint4*>(&w1s[c][c0]);
        __half2 w01 = *(__half2*)&wq.x, w23 = *(__half2*)&wq.y;
        __half2 w45 = *(__half2*)&wq.z, w67 = *(__half2*)&wq.w;
        accA[0] = __hfma2(w01, r0, accA[0]); accB[0] = __hfma2(w01, r1, accB[0]);
        accA[1] = __hfma2(w23, r0, accA[1]); accB[1] = __hfma2(w23, r1, accB[1]);
        accA[2] = __hfma2(w45, r0, accA[2]); accB[2] = __hfma2(w45, r1, accB[2]);
        accA[3] = __hfma2(w67, r0, accA[3]); accB[3] = __hfma2(w67, r1, accB[3]);
    }
#pragma unroll
    for (int q = 0; q < 4; q++) {
        float2 a0 = __half22float2(accA[q]);
        float2 a1 = __half22float2(accB[q]);
        float e0 = a0.x > 0.f ? a0.x : 0.2f*a0.x;
        float e1 = a0.y > 0.f ? a0.y : 0.2f*a0.y;
        float e2 = a1.x > 0.f ? a1.x : 0.2f*a1.x;
        float e3 = a1.y > 0.f ? a1.y : 0.2f*a1.y;
        __half2 p0 = __floats2half2_rn(e0, e2);
        __half2 p1 = __floats2half2_rn(e1, e3);
        act2_s[c0 + 2*q][l]     = *(unsigned int*)&p0;
        act2_s[c0 + 2*q + 1][l] = *(unsigned int*)&p1;
    }
    __syncthreads();

#pragma unroll
    for (int q = 0; q < 4; q++) { accA[q] = pb2h[(c0 >> 1) + q]; accB[q] = accA[q]; }
#pragma unroll 8
    for (int j = 0; j < 64; j++) {
        unsigned int au = act2_s[j][l];
        __half2 ap = *(__half2*)&au;
        __half2 a0 = __half2half2(__low2half(ap));
        __half2 a1 = __half2half2(__high2half(ap));
        uint4 wq = *reinterpret_cast<const uint4*>(&w2s[j][c0]);
        __half2 w01 = *(__half2*)&wq.x, w23 = *(__half2*)&wq.y;
        __half2 w45 = *(__half2*)&wq.z, w67 = *(__half2*)&wq.w;
        accA[0] = __hfma2(w01, a0, accA[0]); accB[0] = __hfma2(w01, a1, accB[0]);
        accA[1] = __hfma2(w23, a0, accA[1]); accB[1] = __hfma2(w23, a1, accB[1]);
        accA[2] = __hfma2(w45, a0, accA[2]); accB[2] = __hfma2(w45, a1, accB[2]);
        accA[3] = __hfma2(w67, a0, accA[3]); accB[3] = __hfma2(w67, a1, accB[3]);
    }
#pragma unroll
    for (int q = 0; q < 4; q++) {
        float2 a0 = __half22float2(accA[q]);
        float2 a1 = __half22float2(accB[q]);
        int ca = c0 + 2*q, cb2 = ca + 1;
        int ba = base + ca*HWn + px0;
        int bb = base + cb2*HWn + px0;
        unsigned int oua = *reinterpret_cast<const unsigned int*>(outp + ba);
        unsigned int oub = *reinterpret_cast<const unsigned int*>(outp + bb);
        float2 oa = __half22float2(*(__half2*)&oua);
        float2 ob = __half22float2(*(__half2*)&oub);
        float la = lss[ca], lb = lss[cb2];
        *reinterpret_cast<float2*>(out + ba) = make_float2(oa.x + la*a0.x, oa.y + la*a1.x);
        *reinterpret_cast<float2*>(out + bb) = make_float2(ob.x + lb*a0.y, ob.y + lb*a1.y);
    }
}

extern "C" void kernel_launch(void* const* d_in, const int* in_sizes, int n_in,
                              void* d_out, int out_size, void* d_ws, size_t ws_size,
                              hipStream_t stream)
{
    (void)in_sizes; (void)n_in; (void)out_size; (void)ws_size;
    const float* force   = (const float*)d_in[0];
    const float* style   = (const float*)d_in[1];
    const float* illum   = (const float*)d_in[2];
    const float* h_w1    = (const float*)d_in[3];
    const float* h_b1    = (const float*)d_in[4];
    const float* h_w2    = (const float*)d_in[5];
    const float* h_b2    = (const float*)d_in[6];
    const float* h_w3    = (const float*)d_in[7];
    const float* h_b3    = (const float*)d_in[8];
    const float* dw_k    = (const float*)d_in[9];
    const float* pw_w    = (const float*)d_in[10];
    const float* r_dw_k  = (const float*)d_in[11];
    const float* r_dw_b  = (const float*)d_in[12];
    const float* r_pw1_w = (const float*)d_in[13];
    const float* r_pw1_b = (const float*)d_in[14];
    const float* r_pw2_w = (const float*)d_in[15];
    const float* r_pw2_b = (const float*)d_in[16];
    const float* lscale  = (const float*)d_in[17];

    float* out  = (float*)d_out;
    float* Xf32 = out + (size_t)NTOT;         // final x fp32
    float* Vf32 = out + 2*(size_t)NTOT;       // final v fp32

    char* w = (char*)d_ws;
    __half2* AB = (__half2*)w; w += (size_t)NTOT*4;
    __half*  F  = (__half*)w;  w += (size_t)NTOT*2;
    __half*  XA = (__half*)w;  w += (size_t)NTOT*2;
    __half*  XB = (__half*)w;  w += (size_t)NTOT*2;
    __half*  Vh = (__half*)w;  w += (size_t)NTOT*2;
    __half*  U2h = (__half*)w; w += (size_t)NPIX*32*2;   // 8.4 MB
    float* w1T  = (float*)w;
    float* c1   = w1T + 2048;
    float* pwT  = c1 + 32;
    float* pw1T = pwT + 4096;
    float* pw2T = pw1T + 4096;
    float* mu   = pw2T + 4096;
    float* rs   = mu + 512;
    __half2* w3abP = (__half2*)(rs + 512);
    __half2* w3gbP = w3abP + 2048;
    __half2* b3abP = w3gbP + 2048;
    __half2* b3gbP = b3abP + 64;
    __half* outp = (__half*)AB;               // AB dead after last osc step

    prep<<<1, 256, 0, stream>>>(style, h_w1, h_b1, pw_w, r_pw1_w, r_pw2_w, h_w3, h_b3,
                                w1T, c1, pwT, pw1T, pw2T, w3abP, w3gbP, b3abP, b3gbP);
    hyperU<<<NPIX/256, 256, 0, stream>>>((const float4*)force, (const float4*)illum,
                                         w1T, c1, h_w2, h_b2, F, XA, Vh, U2h);
    hyperA<<<dim3(NPIX/256, 2), 256, 0, stream>>>(U2h, w3abP, b3abP, AB);
    for (int s = 1; s <= 8; s++) {
        const __half* xin = (s & 1) ? XA : XB;
        __half*      xout = (s & 1) ? XB : XA;
        osc_step<false><<<2048, 256, 0, stream>>>(xin, xout, Vh, F, AB,
                                                  dw_k, pwT, nullptr, nullptr);
    }
    // step 9 (odd): reads XA, writes fp32 x,v directly to d_out
    osc_step<true><<<2048, 256, 0, stream>>>(XA, XB, Vh, F, AB,
                                             dw_k, pwT, Xf32, Vf32);
    inorm_stats<<<Bn*Cn, 256, 0, stream>>>(F, Xf32, mu, rs);
    modGB<<<dim3(NPIX/256, 4), 256, 0, stream>>>(U2h, F, Xf32, w3gbP, b3gbP,
                                                 mu, rs, outp);
    refine<<<NPIX/128, 512, 0, stream>>>(outp, r_dw_k, r_dw_b, pw1T, r_pw1_b,
                                         pw2T, r_pw2_b, lscale, out);
}

// Round 16
// 439.234 us; speedup vs baseline: 2.0760x; 1.0327x over previous
//
#include <hip/hip_runtime.h>
#include <hip/hip_fp16.h>

#define Hn 128
#define Wn 128
#define HWn 16384
#define Cn 64
#define Bn 8
#define NTOT (Bn*Cn*HWn)   /* 8388608 */
#define NPIX (Bn*HWn)      /* 131072  */
#define DTc 0.3f
#define EPSc 1e-5f

__device__ __forceinline__ float sigm(float t){ return 1.0f/(1.0f+__expf(-t)); }

// ---------------- prep: style constant + transposes + packed w3 pairs + zero stats ------
__global__ void prep(const float* __restrict__ style, const float* __restrict__ w1,
                     const float* __restrict__ b1, const float* __restrict__ pw,
                     const float* __restrict__ pw1, const float* __restrict__ pw2,
                     const float* __restrict__ w3, const float* __restrict__ b3,
                     float* __restrict__ w1T, float* __restrict__ c1,
                     float* __restrict__ pwT, float* __restrict__ pw1T,
                     float* __restrict__ pw2T,
                     __half2* __restrict__ w3abP, __half2* __restrict__ w3gbP,
                     __half2* __restrict__ b3abP, __half2* __restrict__ b3gbP,
                     float* __restrict__ Gsum, float* __restrict__ Gsq)
{
    int t = threadIdx.x;
    if (t < 32) {
        float s = b1[t];
        for (int k = 0; k < 64; k++) s += w1[t*128 + 64 + k] * style[k];
        c1[t] = s;
    }
    for (int i = t; i < 2048; i += 256) { int c = i >> 5, j = i & 31; w1T[i] = w1[j*128 + c]; }
    for (int i = t; i < 4096; i += 256) {
        int c = i >> 6, k = i & 63;
        pwT[i]  = pw[k*64 + c];
        pw1T[i] = pw1[k*64 + c];
        pw2T[i] = pw2[k*64 + c];
    }
    for (int i = t; i < 2048; i += 256) {
        int j = i >> 5, k = i & 31;
        w3abP[i] = __floats2half2_rn(w3[j*32 + k],         w3[(64 + j)*32 + k]);
        w3gbP[i] = __floats2half2_rn(w3[(128 + j)*32 + k], w3[(192 + j)*32 + k]);
    }
    if (t < 64) {
        b3abP[t] = __floats2half2_rn(b3[t],       b3[64 + t]);
        b3gbP[t] = __floats2half2_rn(b3[128 + t], b3[192 + t]);
    }
    for (int i = t; i < 512; i += 256) { Gsum[i] = 0.f; Gsq[i] = 0.f; }
}

// ---------------- hyper stage 1 + fused F/XA/V producer ----------------
__global__ __launch_bounds__(256)
void hyperU(const float4* __restrict__ force4, const float4* __restrict__ illum4,
            const float* __restrict__ w1T, const float* __restrict__ c1,
            const float* __restrict__ w2, const float* __restrict__ b2,
            __half* __restrict__ F, __half* __restrict__ XA, __half* __restrict__ Vh,
            __half* __restrict__ U2)
{
    __shared__ __half fs[64][256];
    int t = threadIdx.x;
    int p0 = blockIdx.x << 8;
    int b  = p0 >> 14;
    int sp0 = p0 & (HWn - 1);
    size_t tbase = (size_t)b * Cn * HWn + sp0;
    size_t tb4   = tbase >> 2;

#pragma unroll
    for (int it = 0; it < 16; it++) {
        int f = t + (it << 8);
        int c = f >> 6, u = f & 63;
        size_t gi = tb4 + (size_t)c * (HWn >> 2) + u;
        float4 fv = force4[gi], iv = illum4[gi];
        __half2 h0 = __floats2half2_rn(fv.x + 0.2f*iv.x, fv.y + 0.2f*iv.y);
        __half2 h1 = __floats2half2_rn(fv.z + 0.2f*iv.z, fv.w + 0.2f*iv.w);
        uint2 pk; pk.x = *(unsigned int*)&h0; pk.y = *(unsigned int*)&h1;
        *reinterpret_cast<uint2*>(&fs[c][u << 2]) = pk;
    }
    __syncthreads();

#pragma unroll
    for (int it = 0; it < 8; it++) {
        int f = t + (it << 8);
        int c = f >> 5, u = f & 31;
        uint4 d = *reinterpret_cast<const uint4*>(&fs[c][u << 3]);
        size_t gi = tbase + (size_t)c * HWn + (u << 3);
        *reinterpret_cast<uint4*>(F + gi) = d;
        uint4 xk, vk;
        unsigned int* dp = &d.x;
        unsigned int* xp = &xk.x;
        unsigned int* vp = &vk.x;
#pragma unroll
        for (int q = 0; q < 4; q++) {
            float2 fv = __half22float2(*(__half2*)&dp[q]);
            __half2 hx = __floats2half2_rn(0.09f*fv.x, 0.09f*fv.y);
            __half2 hv = __floats2half2_rn(0.3f*fv.x,  0.3f*fv.y);
            xp[q] = *(unsigned int*)&hx;
            vp[q] = *(unsigned int*)&hv;
        }
        *reinterpret_cast<uint4*>(XA + gi) = xk;
        *reinterpret_cast<uint4*>(Vh + gi) = vk;
    }

    float u1[32];
#pragma unroll
    for (int j = 0; j < 32; j++) u1[j] = c1[j];
#pragma unroll 4
    for (int c = 0; c < 64; c++) {
        float fc = __half2float(fs[c][t]);
        const float* __restrict__ wr = w1T + c*32;
#pragma unroll
        for (int j = 0; j < 32; j++) u1[j] += wr[j] * fc;
    }
#pragma unroll
    for (int j = 0; j < 32; j++) { float v = u1[j]; u1[j] = v > 0.f ? v : 0.2f*v; }

    float u2[32];
#pragma unroll
    for (int i = 0; i < 32; i++) {
        float s = b2[i];
#pragma unroll
        for (int j = 0; j < 32; j++) s += w2[i*32 + j] * u1[j];
        u2[i] = s > 0.f ? s : 0.2f*s;
    }

    uint4* dst = reinterpret_cast<uint4*>(U2 + ((size_t)(p0 + t)) * 32);
#pragma unroll
    for (int q = 0; q < 4; q++) {
        __half2 h0 = __floats2half2_rn(u2[8*q+0], u2[8*q+1]);
        __half2 h1 = __floats2half2_rn(u2[8*q+2], u2[8*q+3]);
        __half2 h2 = __floats2half2_rn(u2[8*q+4], u2[8*q+5]);
        __half2 h3 = __floats2half2_rn(u2[8*q+6], u2[8*q+7]);
        uint4 d;
        d.x = *(unsigned int*)&h0; d.y = *(unsigned int*)&h1;
        d.z = *(unsigned int*)&h2; d.w = *(unsigned int*)&h3;
        dst[q] = d;
    }
}

// ---------------- hyper stage 2: AB only, j-split x2 ----------------
__global__ __launch_bounds__(256)
void hyperA(const __half* __restrict__ U2,
            const __half2* __restrict__ w3abP, const __half2* __restrict__ b3abP,
            __half2* __restrict__ AB)
{
    int p = blockIdx.x * blockDim.x + threadIdx.x;
    int j0 = blockIdx.y << 5;
    int b  = p >> 14;
    int sp = p & (HWn - 1);
    int base = b * Cn * HWn + sp;

    __half2 u2b[32];
    const uint4* src = reinterpret_cast<const uint4*>(U2 + (size_t)p * 32);
#pragma unroll
    for (int q = 0; q < 4; q++) {
        uint4 d = src[q];
        __half2 h;
        h = *(__half2*)&d.x; u2b[8*q+0] = __half2half2(__low2half(h)); u2b[8*q+1] = __half2half2(__high2half(h));
        h = *(__half2*)&d.y; u2b[8*q+2] = __half2half2(__low2half(h)); u2b[8*q+3] = __half2half2(__high2half(h));
        h = *(__half2*)&d.z; u2b[8*q+4] = __half2half2(__low2half(h)); u2b[8*q+5] = __half2half2(__high2half(h));
        h = *(__half2*)&d.w; u2b[8*q+6] = __half2half2(__low2half(h)); u2b[8*q+7] = __half2half2(__high2half(h));
    }

#pragma unroll 2
    for (int jj = 0; jj < 32; jj++) {
        int j = j0 + jj;
        __half2 aab = b3abP[j];
        const __half2* __restrict__ wa = w3abP + j*32;
#pragma unroll
        for (int i = 0; i < 32; i++) aab = __hfma2(wa[i], u2b[i], aab);
        float2 tab = __half22float2(aab);
        float om = 2.0f * sigm(tab.x);
        float ze = sigm(tab.y);
        AB[base + j*HWn] = __floats2half2_rn(2.0f * ze * om, om * om);
    }
}

// ---------------- oscillator step (R12-frozen structure; LAST fuses inorm partials) -----
template <bool LAST>
__global__ void osc_step(const __half* __restrict__ Xin, __half* __restrict__ Xout,
                         __half* __restrict__ V, const __half* __restrict__ F,
                         const __half2* __restrict__ AB,
                         const float* __restrict__ dwk, const float* __restrict__ pwT,
                         float* __restrict__ Xf, float* __restrict__ Vf,
                         float* __restrict__ Gsum, float* __restrict__ Gsq)
{
    int wid  = blockIdx.x;
    int slot = wid >> 3;
    int pc   = ((wid & 7) << 6) + (slot >> 2);   // pixel-chunk 0..511
    int c0   = (slot & 3) << 4;                  // channel group start
    int t = threadIdx.x;
    int p = (pc << 8) + t;
    int b  = p >> 14;
    int sp = p & (HWn - 1);
    int y = sp >> 7, x = sp & 127;
    int base = b * Cn * HWn + sp;

    float acc[16];
#pragma unroll
    for (int k = 0; k < 16; k++) acc[k] = 0.f;
#pragma unroll 8
    for (int c = 0; c < 64; c++) {
        float xc = __half2float(Xin[base + c*HWn]);
        const float* __restrict__ wr = pwT + c*64 + c0;
#pragma unroll
        for (int k = 0; k < 16; k++) acc[k] += wr[k] * xc;
    }

    int   yo[3] = { y > 0 ? -Wn : 0, 0, y < Hn-1 ? Wn : 0 };
    int   xo[3] = { x > 0 ? -1  : 0, 0, x < Wn-1 ? 1  : 0 };
    float my[3] = { y > 0 ? 1.f : 0.f, 1.f, y < Hn-1 ? 1.f : 0.f };
    float mx[3] = { x > 0 ? 1.f : 0.f, 1.f, x < Wn-1 ? 1.f : 0.f };
    float mm[9]; int oo[9];
#pragma unroll
    for (int dy = 0; dy < 3; dy++)
#pragma unroll
        for (int dx = 0; dx < 3; dx++) { mm[dy*3+dx] = my[dy]*mx[dx]; oo[dy*3+dx] = yo[dy]+xo[dx]; }

#pragma unroll
    for (int cc = 0; cc < 16; cc++) {
        int c = c0 + cc;
        int cb = base + c*HWn;
        float2 ab = __half22float2(AB[cb]);
        float vv = __half2float(V[cb]);
        float ff = __half2float(F[cb]);
        float tv[9];
#pragma unroll
        for (int tt = 0; tt < 9; tt++) tv[tt] = __half2float(Xin[cb + oo[tt]]);
        float dws = 0.f;
#pragma unroll
        for (int tt = 0; tt < 9; tt++) dws += (dwk[c*9 + tt] * mm[tt]) * tv[tt];
        float xc = tv[4];
        float accel = ff + acc[cc] + dws - ab.x * vv - ab.y * xc;
        vv += accel * DTc;
        float xn = xc + vv * DTc;
        if constexpr (!LAST) {
            V[cb] = __float2half(vv);
            Xout[cb] = __float2half(xn);
        } else {
            Xf[cb] = xn;
            Vf[cb] = vv;
            // fused instance-norm partial sums over fx = F + x
            __shared__ float ssum[16][4], ssq[16][4];
            float fx = ff + xn;
            float s = fx, q = fx*fx;
#pragma unroll
            for (int o = 32; o > 0; o >>= 1) { s += __shfl_down(s, o); q += __shfl_down(q, o); }
            int lane = t & 63, wv = t >> 6;
            if (lane == 0) { ssum[cc][wv] = s; ssq[cc][wv] = q; }
            if (cc == 15) {
                __syncthreads();
                if (t < 16) {
                    float S = ssum[t][0] + ssum[t][1] + ssum[t][2] + ssum[t][3];
                    float Q = ssq[t][0]  + ssq[t][1]  + ssq[t][2]  + ssq[t][3];
                    atomicAdd(&Gsum[b*64 + c0 + t], S);
                    atomicAdd(&Gsq[b*64 + c0 + t], Q);
                }
            }
        }
    }
}

// ---------------- finalize instance-norm stats ----------------
__global__ void inorm_fin(const float* __restrict__ Gsum, const float* __restrict__ Gsq,
                          float* __restrict__ mu, float* __restrict__ rs)
{
    int i = threadIdx.x + blockIdx.x * blockDim.x;    // 512
    float m = Gsum[i] / (float)HWn;
    float var = Gsq[i] / (float)HWn - m*m;
    mu[i] = m;
    rs[i] = rsqrtf(var + EPSc);
}

// ---------------- fused gamma/beta + instance-norm modulation -> outp (fp16) ------------
__global__ __launch_bounds__(256)
void modGB(const __half* __restrict__ U2, const __half* __restrict__ F,
           const float* __restrict__ X,
           const __half2* __restrict__ w3gbP, const __half2* __restrict__ b3gbP,
           const float* __restrict__ mu, const float* __restrict__ rs,
           __half* __restrict__ outp)
{
    int p = blockIdx.x * blockDim.x + threadIdx.x;
    int j0 = blockIdx.y << 4;
    int b  = p >> 14;
    int sp = p & (HWn - 1);
    int base = b * Cn * HWn + sp;

    __half2 u2b[32];
    const uint4* src = reinterpret_cast<const uint4*>(U2 + (size_t)p * 32);
#pragma unroll
    for (int q = 0; q < 4; q++) {
        uint4 d = src[q];
        __half2 h;
        h = *(__half2*)&d.x; u2b[8*q+0] = __half2half2(__low2half(h)); u2b[8*q+1] = __half2half2(__high2half(h));
        h = *(__half2*)&d.y; u2b[8*q+2] = __half2half2(__low2half(h)); u2b[8*q+3] = __half2half2(__high2half(h));
        h = *(__half2*)&d.z; u2b[8*q+4] = __half2half2(__low2half(h)); u2b[8*q+5] = __half2half2(__high2half(h));
        h = *(__half2*)&d.w; u2b[8*q+6] = __half2half2(__low2half(h)); u2b[8*q+7] = __half2half2(__high2half(h));
    }

#pragma unroll 2
    for (int jj = 0; jj < 16; jj++) {
        int j = j0 + jj;
        __half2 agb = b3gbP[j];
        const __half2* __restrict__ wg = w3gbP + j*32;
#pragma unroll
        for (int i = 0; i < 32; i++) agb = __hfma2(wg[i], u2b[i], agb);
        float2 tgb = __half22float2(agb);
        float gamma = 2.0f * sigm(tgb.x);
        float beta  = tanhf(tgb.y);
        int cb = base + j*HWn;
        int bc = b*64 + j;
        float fx = __half2float(F[cb]) + X[cb];
        float o = gamma * ((fx - mu[bc]) * rs[bc]) + beta;
        outp[cb] = __float2half(o);
    }
}

// ---------------- refine v3 (FROZEN) ----------------
__global__ __launch_bounds__(512)
void refine(const __half* __restrict__ outp,
            const float* __restrict__ rdwk, const float* __restrict__ rdwb,
            const float* __restrict__ pw1T, const float* __restrict__ pb1,
            const float* __restrict__ pw2T, const float* __restrict__ pb2,
            const float* __restrict__ ls, float* __restrict__ out)
{
    __shared__ unsigned int rv2_s[64][64];
    __shared__ unsigned int act2_s[64][64];
    __shared__ __half w1s[64][64];
    __shared__ __half w2s[64][64];
    __shared__ float  dwks[576];
    __shared__ __half2 pb1h[32], pb2h[32];
    __shared__ float  rdwbs[64], lss[64];
    int t = threadIdx.x;
    for (int i = t; i < 4096; i += 512) {
        w1s[i>>6][i&63] = __float2half(pw1T[i]);
        w2s[i>>6][i&63] = __float2half(pw2T[i]);
    }
    for (int i = t; i < 576; i += 512) dwks[i] = rdwk[i];
    if (t < 64) { rdwbs[t]=rdwb[t]; lss[t]=ls[t]; }
    if (t < 32) {
        pb1h[t] = __floats2half2_rn(pb1[2*t], pb1[2*t+1]);
        pb2h[t] = __floats2half2_rn(pb2[2*t], pb2[2*t+1]);
    }

    int l  = t & 63;
    int g  = t >> 6;
    int c0 = g << 3;
    int row = blockIdx.x;
    int b = row >> 7, y = row & 127;
    int base = b * Cn * HWn + y * Wn;
    int px0 = l << 1;

    int   yo[3] = { y > 0 ? -Wn : 0, 0, y < Hn-1 ? Wn : 0 };
    float my[3] = { y > 0 ? 1.f : 0.f, 1.f, y < Hn-1 ? 1.f : 0.f };
    float wl = l > 0  ? 1.f : 0.f;
    float wr = l < 63 ? 1.f : 0.f;
    int loff = l > 0 ? -1 : 0;
    __syncthreads();

#pragma unroll
    for (int cc = 0; cc < 8; cc++) {
        int c = c0 + cc;
        int cb = base + c*HWn + px0;
        float rv0 = rdwbs[c], rv1 = rdwbs[c];
#pragma unroll
        for (int r = 0; r < 3; r++) {
            const __half* __restrict__ rp = outp + cb + yo[r];
            unsigned int cu = *reinterpret_cast<const unsigned int*>(rp);
            float2 ct = __half22float2(*(__half2*)&cu);
            float lf = __half2float(rp[loff]);
            float rt = __half2float(rp[2]);
            float k0 = dwks[c*9 + r*3 + 0] * my[r];
            float k1 = dwks[c*9 + r*3 + 1] * my[r];
            float k2 = dwks[c*9 + r*3 + 2] * my[r];
            rv0 += k0*(wl*lf) + k1*ct.x + k2*ct.y;
            rv1 += k0*ct.x + k1*ct.y + k2*(wr*rt);
        }
        __half2 hv = __floats2half2_rn(rv0, rv1);
        rv2_s[c][l] = *(unsigned int*)&hv;
    }
    __syncthreads();

    __half2 accA[4], accB[4];
#pragma unroll
    for (int q = 0; q < 4; q++) { accA[q] = pb1h[(c0 >> 1) + q]; accB[q] = accA[q]; }
#pragma unroll 8
    for (int c = 0; c < 64; c++) {
        unsigned int rvu = rv2_s[c][l];
        __half2 rvp = *(__half2*)&rvu;
        __half2 r0 = __half2half2(__low2half(rvp));
        __half2 r1 = __half2half2(__high2half(rvp));
        uint4 wq = *reinterpret_cast<const uint4*>(&w1s[c][c0]);
        __half2 w01 = *(__half2*)&wq.x, w23 = *(__half2*)&wq.y;
        __half2 w45 = *(__half2*)&wq.z, w67 = *(__half2*)&wq.w;
        accA[0] = __hfma2(w01, r0, accA[0]); accB[0] = __hfma2(w01, r1, accB[0]);
        accA[1] = __hfma2(w23, r0, accA[1]); accB[1] = __hfma2(w23, r1, accB[1]);
        accA[2] = __hfma2(w45, r0, accA[2]); accB[2] = __hfma2(w45, r1, accB[2]);
        accA[3] = __hfma2(w67, r0, accA[3]); accB[3] = __hfma2(w67, r1, accB[3]);
    }
#pragma unroll
    for (int q = 0; q < 4; q++) {
        float2 a0 = __half22float2(accA[q]);
        float2 a1 = __half22float2(accB[q]);
        float e0 = a0.x > 0.f ? a0.x : 0.2f*a0.x;
        float e1 = a0.y > 0.f ? a0.y : 0.2f*a0.y;
        float e2 = a1.x > 0.f ? a1.x : 0.2f*a1.x;
        float e3 = a1.y > 0.f ? a1.y : 0.2f*a1.y;
        __half2 p0 = __floats2half2_rn(e0, e2);
        __half2 p1 = __floats2half2_rn(e1, e3);
        act2_s[c0 + 2*q][l]     = *(unsigned int*)&p0;
        act2_s[c0 + 2*q + 1][l] = *(unsigned int*)&p1;
    }
    __syncthreads();

#pragma unroll
    for (int q = 0; q < 4; q++) { accA[q] = pb2h[(c0 >> 1) + q]; accB[q] = accA[q]; }
#pragma unroll 8
    for (int j = 0; j < 64; j++) {
        unsigned int au = act2_s[j][l];
        __half2 ap = *(__half2*)&au;
        __half2 a0 = __half2half2(__low2half(ap));
        __half2 a1 = __half2half2(__high2half(ap));
        uint4 wq = *reinterpret_cast<const uint4*>(&w2s[j][c0]);
        __half2 w01 = *(__half2*)&wq.x, w23 = *(__half2*)&wq.y;
        __half2 w45 = *(__half2*)&wq.z, w67 = *(__half2*)&wq.w;
        accA[0] = __hfma2(w01, a0, accA[0]); accB[0] = __hfma2(w01, a1, accB[0]);
        accA[1] = __hfma2(w23, a0, accA[1]); accB[1] = __hfma2(w23, a1, accB[1]);
        accA[2] = __hfma2(w45, a0, accA[2]); accB[2] = __hfma2(w45, a1, accB[2]);
        accA[3] = __hfma2(w67, a0, accA[3]); accB[3] = __hfma2(w67, a1, accB[3]);
    }
#pragma unroll
    for (int q = 0; q < 4; q++) {
        float2 a0 = __half22float2(accA[q]);
        float2 a1 = __half22float2(accB[q]);
        int ca = c0 + 2*q, cb2 = ca + 1;
        int ba = base + ca*HWn + px0;
        int bb = base + cb2*HWn + px0;
        unsigned int oua = *reinterpret_cast<const unsigned int*>(outp + ba);
        unsigned int oub = *reinterpret_cast<const unsigned int*>(outp + bb);
        float2 oa = __half22float2(*(__half2*)&oua);
        float2 ob = __half22float2(*(__half2*)&oub);
        float la = lss[ca], lb = lss[cb2];
        *reinterpret_cast<float2*>(out + ba) = make_float2(oa.x + la*a0.x, oa.y + la*a1.x);
        *reinterpret_cast<float2*>(out + bb) = make_float2(ob.x + lb*a0.y, ob.y + lb*a1.y);
    }
}

extern "C" void kernel_launch(void* const* d_in, const int* in_sizes, int n_in,
                              void* d_out, int out_size, void* d_ws, size_t ws_size,
                              hipStream_t stream)
{
    (void)in_sizes; (void)n_in; (void)out_size; (void)ws_size;
    const float* force   = (const float*)d_in[0];
    const float* style   = (const float*)d_in[1];
    const float* illum   = (const float*)d_in[2];
    const float* h_w1    = (const float*)d_in[3];
    const float* h_b1    = (const float*)d_in[4];
    const float* h_w2    = (const float*)d_in[5];
    const float* h_b2    = (const float*)d_in[6];
    const float* h_w3    = (const float*)d_in[7];
    const float* h_b3    = (const float*)d_in[8];
    const float* dw_k    = (const float*)d_in[9];
    const float* pw_w    = (const float*)d_in[10];
    const float* r_dw_k  = (const float*)d_in[11];
    const float* r_dw_b  = (const float*)d_in[12];
    const float* r_pw1_w = (const float*)d_in[13];
    const float* r_pw1_b = (const float*)d_in[14];
    const float* r_pw2_w = (const float*)d_in[15];
    const float* r_pw2_b = (const float*)d_in[16];
    const float* lscale  = (const float*)d_in[17];

    float* out  = (float*)d_out;
    float* Xf32 = out + (size_t)NTOT;         // final x fp32
    float* Vf32 = out + 2*(size_t)NTOT;       // final v fp32

    char* w = (char*)d_ws;
    __half2* AB = (__half2*)w; w += (size_t)NTOT*4;
    __half*  F  = (__half*)w;  w += (size_t)NTOT*2;
    __half*  XA = (__half*)w;  w += (size_t)NTOT*2;
    __half*  XB = (__half*)w;  w += (size_t)NTOT*2;
    __half*  Vh = (__half*)w;  w += (size_t)NTOT*2;
    __half*  U2h = (__half*)w; w += (size_t)NPIX*32*2;   // 8.4 MB
    float* w1T  = (float*)w;
    float* c1   = w1T + 2048;
    float* pwT  = c1 + 32;
    float* pw1T = pwT + 4096;
    float* pw2T = pw1T + 4096;
    float* mu   = pw2T + 4096;
    float* rs   = mu + 512;
    __half2* w3abP = (__half2*)(rs + 512);
    __half2* w3gbP = w3abP + 2048;
    __half2* b3abP = w3gbP + 2048;
    __half2* b3gbP = b3abP + 64;
    float* Gsum = (float*)(b3gbP + 64);
    float* Gsq  = Gsum + 512;
    __half* outp = (__half*)AB;               // AB dead after last osc step

    prep<<<1, 256, 0, stream>>>(style, h_w1, h_b1, pw_w, r_pw1_w, r_pw2_w, h_w3, h_b3,
                                w1T, c1, pwT, pw1T, pw2T, w3abP, w3gbP, b3abP, b3gbP,
                                Gsum, Gsq);
    hyperU<<<NPIX/256, 256, 0, stream>>>((const float4*)force, (const float4*)illum,
                                         w1T, c1, h_w2, h_b2, F, XA, Vh, U2h);
    hyperA<<<dim3(NPIX/256, 2), 256, 0, stream>>>(U2h, w3abP, b3abP, AB);
    for (int s = 1; s <= 8; s++) {
        const __half* xin = (s & 1) ? XA : XB;
        __half*      xout = (s & 1) ? XB : XA;
        osc_step<false><<<2048, 256, 0, stream>>>(xin, xout, Vh, F, AB,
                                                  dw_k, pwT, nullptr, nullptr,
                                                  nullptr, nullptr);
    }
    // step 9 (odd): reads XA, writes fp32 x,v to d_out + fused inorm partial sums
    osc_step<true><<<2048, 256, 0, stream>>>(XA, XB, Vh, F, AB,
                                             dw_k, pwT, Xf32, Vf32, Gsum, Gsq);
    inorm_fin<<<2, 256, 0, stream>>>(Gsum, Gsq, mu, rs);
    modGB<<<dim3(NPIX/256, 4), 256, 0, stream>>>(U2h, F, Xf32, w3gbP, b3gbP,
                                                 mu, rs, outp);
    refine<<<NPIX/128, 512, 0, stream>>>(outp, r_dw_k, r_dw_b, pw1T, r_pw1_b,
                                         pw2T, r_pw2_b, lscale, out);
}

// Round 17
// 434.572 us; speedup vs baseline: 2.0983x; 1.0107x over previous
//
#include <hip/hip_runtime.h>
#include <hip/hip_fp16.h>

#define Hn 128
#define Wn 128
#define HWn 16384
#define Cn 64
#define Bn 8
#define NTOT (Bn*Cn*HWn)   /* 8388608 */
#define NPIX (Bn*HWn)      /* 131072  */
#define DTc 0.3f
#define EPSc 1e-5f

__device__ __forceinline__ float sigm(float t){ return 1.0f/(1.0f+__expf(-t)); }

// ---------------- prep: style constant + transposes + packed w3 pairs + zero stats ------
__global__ void prep(const float* __restrict__ style, const float* __restrict__ w1,
                     const float* __restrict__ b1, const float* __restrict__ pw,
                     const float* __restrict__ pw1, const float* __restrict__ pw2,
                     const float* __restrict__ w3, const float* __restrict__ b3,
                     float* __restrict__ w1T, float* __restrict__ c1,
                     float* __restrict__ pwT, float* __restrict__ pw1T,
                     float* __restrict__ pw2T,
                     __half2* __restrict__ w3abP, __half2* __restrict__ w3gbP,
                     __half2* __restrict__ b3abP, __half2* __restrict__ b3gbP,
                     float* __restrict__ Gsum, float* __restrict__ Gsq)
{
    int t = threadIdx.x;
    if (t < 32) {
        float s = b1[t];
        for (int k = 0; k < 64; k++) s += w1[t*128 + 64 + k] * style[k];
        c1[t] = s;
    }
    for (int i = t; i < 2048; i += 256) { int c = i >> 5, j = i & 31; w1T[i] = w1[j*128 + c]; }
    for (int i = t; i < 4096; i += 256) {
        int c = i >> 6, k = i & 63;
        pwT[i]  = pw[k*64 + c];
        pw1T[i] = pw1[k*64 + c];
        pw2T[i] = pw2[k*64 + c];
    }
    for (int i = t; i < 2048; i += 256) {
        int j = i >> 5, k = i & 31;
        w3abP[i] = __floats2half2_rn(w3[j*32 + k],         w3[(64 + j)*32 + k]);
        w3gbP[i] = __floats2half2_rn(w3[(128 + j)*32 + k], w3[(192 + j)*32 + k]);
    }
    if (t < 64) {
        b3abP[t] = __floats2half2_rn(b3[t],       b3[64 + t]);
        b3gbP[t] = __floats2half2_rn(b3[128 + t], b3[192 + t]);
    }
    for (int i = t; i < 512; i += 256) { Gsum[i] = 0.f; Gsq[i] = 0.f; }
}

// ---------------- hyper stage 1 + fused F/XA/V producer ----------------
__global__ __launch_bounds__(256)
void hyperU(const float4* __restrict__ force4, const float4* __restrict__ illum4,
            const float* __restrict__ w1T, const float* __restrict__ c1,
            const float* __restrict__ w2, const float* __restrict__ b2,
            __half* __restrict__ F, __half* __restrict__ XA, __half* __restrict__ Vh,
            __half* __restrict__ U2)
{
    __shared__ __half fs[64][256];
    int t = threadIdx.x;
    int p0 = blockIdx.x << 8;
    int b  = p0 >> 14;
    int sp0 = p0 & (HWn - 1);
    size_t tbase = (size_t)b * Cn * HWn + sp0;
    size_t tb4   = tbase >> 2;

#pragma unroll
    for (int it = 0; it < 16; it++) {
        int f = t + (it << 8);
        int c = f >> 6, u = f & 63;
        size_t gi = tb4 + (size_t)c * (HWn >> 2) + u;
        float4 fv = force4[gi], iv = illum4[gi];
        __half2 h0 = __floats2half2_rn(fv.x + 0.2f*iv.x, fv.y + 0.2f*iv.y);
        __half2 h1 = __floats2half2_rn(fv.z + 0.2f*iv.z, fv.w + 0.2f*iv.w);
        uint2 pk; pk.x = *(unsigned int*)&h0; pk.y = *(unsigned int*)&h1;
        *reinterpret_cast<uint2*>(&fs[c][u << 2]) = pk;
    }
    __syncthreads();

#pragma unroll
    for (int it = 0; it < 8; it++) {
        int f = t + (it << 8);
        int c = f >> 5, u = f & 31;
        uint4 d = *reinterpret_cast<const uint4*>(&fs[c][u << 3]);
        size_t gi = tbase + (size_t)c * HWn + (u << 3);
        *reinterpret_cast<uint4*>(F + gi) = d;
        uint4 xk, vk;
        unsigned int* dp = &d.x;
        unsigned int* xp = &xk.x;
        unsigned int* vp = &vk.x;
#pragma unroll
        for (int q = 0; q < 4; q++) {
            float2 fv = __half22float2(*(__half2*)&dp[q]);
            __half2 hx = __floats2half2_rn(0.09f*fv.x, 0.09f*fv.y);
            __half2 hv = __floats2half2_rn(0.3f*fv.x,  0.3f*fv.y);
            xp[q] = *(unsigned int*)&hx;
            vp[q] = *(unsigned int*)&hv;
        }
        *reinterpret_cast<uint4*>(XA + gi) = xk;
        *reinterpret_cast<uint4*>(Vh + gi) = vk;
    }

    float u1[32];
#pragma unroll
    for (int j = 0; j < 32; j++) u1[j] = c1[j];
#pragma unroll 4
    for (int c = 0; c < 64; c++) {
        float fc = __half2float(fs[c][t]);
        const float* __restrict__ wr = w1T + c*32;
#pragma unroll
        for (int j = 0; j < 32; j++) u1[j] += wr[j] * fc;
    }
#pragma unroll
    for (int j = 0; j < 32; j++) { float v = u1[j]; u1[j] = v > 0.f ? v : 0.2f*v; }

    float u2[32];
#pragma unroll
    for (int i = 0; i < 32; i++) {
        float s = b2[i];
#pragma unroll
        for (int j = 0; j < 32; j++) s += w2[i*32 + j] * u1[j];
        u2[i] = s > 0.f ? s : 0.2f*s;
    }

    uint4* dst = reinterpret_cast<uint4*>(U2 + ((size_t)(p0 + t)) * 32);
#pragma unroll
    for (int q = 0; q < 4; q++) {
        __half2 h0 = __floats2half2_rn(u2[8*q+0], u2[8*q+1]);
        __half2 h1 = __floats2half2_rn(u2[8*q+2], u2[8*q+3]);
        __half2 h2 = __floats2half2_rn(u2[8*q+4], u2[8*q+5]);
        __half2 h3 = __floats2half2_rn(u2[8*q+6], u2[8*q+7]);
        uint4 d;
        d.x = *(unsigned int*)&h0; d.y = *(unsigned int*)&h1;
        d.z = *(unsigned int*)&h2; d.w = *(unsigned int*)&h3;
        dst[q] = d;
    }
}

// ---------------- hyper stage 2: AB only, j-split x2 ----------------
__global__ __launch_bounds__(256)
void hyperA(const __half* __restrict__ U2,
            const __half2* __restrict__ w3abP, const __half2* __restrict__ b3abP,
            __half2* __restrict__ AB)
{
    int p = blockIdx.x * blockDim.x + threadIdx.x;
    int j0 = blockIdx.y << 5;
    int b  = p >> 14;
    int sp = p & (HWn - 1);
    int base = b * Cn * HWn + sp;

    __half2 u2b[32];
    const uint4* src = reinterpret_cast<const uint4*>(U2 + (size_t)p * 32);
#pragma unroll
    for (int q = 0; q < 4; q++) {
        uint4 d = src[q];
        __half2 h;
        h = *(__half2*)&d.x; u2b[8*q+0] = __half2half2(__low2half(h)); u2b[8*q+1] = __half2half2(__high2half(h));
        h = *(__half2*)&d.y; u2b[8*q+2] = __half2half2(__low2half(h)); u2b[8*q+3] = __half2half2(__high2half(h));
        h = *(__half2*)&d.z; u2b[8*q+4] = __half2half2(__low2half(h)); u2b[8*q+5] = __half2half2(__high2half(h));
        h = *(__half2*)&d.w; u2b[8*q+6] = __half2half2(__low2half(h)); u2b[8*q+7] = __half2half2(__high2half(h));
    }

#pragma unroll 2
    for (int jj = 0; jj < 32; jj++) {
        int j = j0 + jj;
        __half2 aab = b3abP[j];
        const __half2* __restrict__ wa = w3abP + j*32;
#pragma unroll
        for (int i = 0; i < 32; i++) aab = __hfma2(wa[i], u2b[i], aab);
        float2 tab = __half22float2(aab);
        float om = 2.0f * sigm(tab.x);
        float ze = sigm(tab.y);
        AB[base + j*HWn] = __floats2half2_rn(2.0f * ze * om, om * om);
    }
}

// ---------------- oscillator step (R12-frozen structure; LAST fuses inorm partials) -----
template <bool LAST>
__global__ void osc_step(const __half* __restrict__ Xin, __half* __restrict__ Xout,
                         __half* __restrict__ V, const __half* __restrict__ F,
                         const __half2* __restrict__ AB,
                         const float* __restrict__ dwk, const float* __restrict__ pwT,
                         float* __restrict__ Xf, float* __restrict__ Vf,
                         float* __restrict__ Gsum, float* __restrict__ Gsq)
{
    int wid  = blockIdx.x;
    int slot = wid >> 3;
    int pc   = ((wid & 7) << 6) + (slot >> 2);   // pixel-chunk 0..511
    int c0   = (slot & 3) << 4;                  // channel group start
    int t = threadIdx.x;
    int p = (pc << 8) + t;
    int b  = p >> 14;
    int sp = p & (HWn - 1);
    int y = sp >> 7, x = sp & 127;
    int base = b * Cn * HWn + sp;

    float acc[16];
#pragma unroll
    for (int k = 0; k < 16; k++) acc[k] = 0.f;
#pragma unroll 8
    for (int c = 0; c < 64; c++) {
        float xc = __half2float(Xin[base + c*HWn]);
        const float* __restrict__ wr = pwT + c*64 + c0;
#pragma unroll
        for (int k = 0; k < 16; k++) acc[k] += wr[k] * xc;
    }

    int   yo[3] = { y > 0 ? -Wn : 0, 0, y < Hn-1 ? Wn : 0 };
    int   xo[3] = { x > 0 ? -1  : 0, 0, x < Wn-1 ? 1  : 0 };
    float my[3] = { y > 0 ? 1.f : 0.f, 1.f, y < Hn-1 ? 1.f : 0.f };
    float mx[3] = { x > 0 ? 1.f : 0.f, 1.f, x < Wn-1 ? 1.f : 0.f };
    float mm[9]; int oo[9];
#pragma unroll
    for (int dy = 0; dy < 3; dy++)
#pragma unroll
        for (int dx = 0; dx < 3; dx++) { mm[dy*3+dx] = my[dy]*mx[dx]; oo[dy*3+dx] = yo[dy]+xo[dx]; }

#pragma unroll
    for (int cc = 0; cc < 16; cc++) {
        int c = c0 + cc;
        int cb = base + c*HWn;
        float2 ab = __half22float2(AB[cb]);
        float vv = __half2float(V[cb]);
        float ff = __half2float(F[cb]);
        float tv[9];
#pragma unroll
        for (int tt = 0; tt < 9; tt++) tv[tt] = __half2float(Xin[cb + oo[tt]]);
        float dws = 0.f;
#pragma unroll
        for (int tt = 0; tt < 9; tt++) dws += (dwk[c*9 + tt] * mm[tt]) * tv[tt];
        float xc = tv[4];
        float accel = ff + acc[cc] + dws - ab.x * vv - ab.y * xc;
        vv += accel * DTc;
        float xn = xc + vv * DTc;
        if constexpr (!LAST) {
            V[cb] = __float2half(vv);
            Xout[cb] = __float2half(xn);
        } else {
            Xf[cb] = xn;
            Vf[cb] = vv;
            // fused instance-norm partial sums over fx = F + x
            __shared__ float ssum[16][4], ssq[16][4];
            float fx = ff + xn;
            float s = fx, q = fx*fx;
#pragma unroll
            for (int o = 32; o > 0; o >>= 1) { s += __shfl_down(s, o); q += __shfl_down(q, o); }
            int lane = t & 63, wv = t >> 6;
            if (lane == 0) { ssum[cc][wv] = s; ssq[cc][wv] = q; }
            if (cc == 15) {
                __syncthreads();
                if (t < 16) {
                    float S = ssum[t][0] + ssum[t][1] + ssum[t][2] + ssum[t][3];
                    float Q = ssq[t][0]  + ssq[t][1]  + ssq[t][2]  + ssq[t][3];
                    atomicAdd(&Gsum[b*64 + c0 + t], S);
                    atomicAdd(&Gsq[b*64 + c0 + t], Q);
                }
            }
        }
    }
}

// ---------------- finalize instance-norm stats ----------------
__global__ void inorm_fin(const float* __restrict__ Gsum, const float* __restrict__ Gsq,
                          float* __restrict__ mu, float* __restrict__ rs)
{
    int i = threadIdx.x + blockIdx.x * blockDim.x;    // 512
    float m = Gsum[i] / (float)HWn;
    float var = Gsq[i] / (float)HWn - m*m;
    mu[i] = m;
    rs[i] = rsqrtf(var + EPSc);
}

// ---------------- fused gamma/beta + instance-norm modulation -> outp (fp16) ------------
__global__ __launch_bounds__(256)
void modGB(const __half* __restrict__ U2, const __half* __restrict__ F,
           const float* __restrict__ X,
           const __half2* __restrict__ w3gbP, const __half2* __restrict__ b3gbP,
           const float* __restrict__ mu, const float* __restrict__ rs,
           __half* __restrict__ outp)
{
    int p = blockIdx.x * blockDim.x + threadIdx.x;
    int j0 = blockIdx.y << 4;
    int b  = p >> 14;
    int sp = p & (HWn - 1);
    int base = b * Cn * HWn + sp;

    __half2 u2b[32];
    const uint4* src = reinterpret_cast<const uint4*>(U2 + (size_t)p * 32);
#pragma unroll
    for (int q = 0; q < 4; q++) {
        uint4 d = src[q];
        __half2 h;
        h = *(__half2*)&d.x; u2b[8*q+0] = __half2half2(__low2half(h)); u2b[8*q+1] = __half2half2(__high2half(h));
        h = *(__half2*)&d.y; u2b[8*q+2] = __half2half2(__low2half(h)); u2b[8*q+3] = __half2half2(__high2half(h));
        h = *(__half2*)&d.z; u2b[8*q+4] = __half2half2(__low2half(h)); u2b[8*q+5] = __half2half2(__high2half(h));
        h = *(__half2*)&d.w; u2b[8*q+6] = __half2half2(__low2half(h)); u2b[8*q+7] = __half2half2(__high2half(h));
    }

#pragma unroll 2
    for (int jj = 0; jj < 16; jj++) {
        int j = j0 + jj;
        __half2 agb = b3gbP[j];
        const __half2* __restrict__ wg = w3gbP + j*32;
#pragma unroll
        for (int i = 0; i < 32; i++) agb = __hfma2(wg[i], u2b[i], agb);
        float2 tgb = __half22float2(agb);
        float gamma = 2.0f * sigm(tgb.x);
        float beta  = tanhf(tgb.y);
        int cb = base + j*HWn;
        int bc = b*64 + j;
        float fx = __half2float(F[cb]) + X[cb];
        float o = gamma * ((fx - mu[bc]) * rs[bc]) + beta;
        outp[cb] = __float2half(o);
    }
}

// ---------------- refine v4: shared rv/act buffer (35.8 KB LDS -> 4 blocks/CU) ----------
__global__ __launch_bounds__(512)
void refine(const __half* __restrict__ outp,
            const float* __restrict__ rdwk, const float* __restrict__ rdwb,
            const float* __restrict__ pw1T, const float* __restrict__ pb1,
            const float* __restrict__ pw2T, const float* __restrict__ pb2,
            const float* __restrict__ ls, float* __restrict__ out)
{
    __shared__ unsigned int buf_s[64][64];    // rv (phase1/2), then act (phase2/3), 16KB
    __shared__ __half w1s[64][64];            // 8KB
    __shared__ __half w2s[64][64];            // 8KB
    __shared__ float  dwks[576];
    __shared__ __half2 pb1h[32], pb2h[32];
    __shared__ float  rdwbs[64], lss[64];
    int t = threadIdx.x;
    for (int i = t; i < 4096; i += 512) {
        w1s[i>>6][i&63] = __float2half(pw1T[i]);
        w2s[i>>6][i&63] = __float2half(pw2T[i]);
    }
    for (int i = t; i < 576; i += 512) dwks[i] = rdwk[i];
    if (t < 64) { rdwbs[t]=rdwb[t]; lss[t]=ls[t]; }
    if (t < 32) {
        pb1h[t] = __floats2half2_rn(pb1[2*t], pb1[2*t+1]);
        pb2h[t] = __floats2half2_rn(pb2[2*t], pb2[2*t+1]);
    }

    int l  = t & 63;
    int g  = t >> 6;
    int c0 = g << 3;
    int row = blockIdx.x;
    int b = row >> 7, y = row & 127;
    int base = b * Cn * HWn + y * Wn;
    int px0 = l << 1;

    int   yo[3] = { y > 0 ? -Wn : 0, 0, y < Hn-1 ? Wn : 0 };
    float my[3] = { y > 0 ? 1.f : 0.f, 1.f, y < Hn-1 ? 1.f : 0.f };
    float wl = l > 0  ? 1.f : 0.f;
    float wr = l < 63 ? 1.f : 0.f;
    int loff = l > 0 ? -1 : 0;
    __syncthreads();

    // ---- phase 1: depthwise conv, 2 px x 8 ch -> rv into buf_s ----
#pragma unroll
    for (int cc = 0; cc < 8; cc++) {
        int c = c0 + cc;
        int cb = base + c*HWn + px0;
        float rv0 = rdwbs[c], rv1 = rdwbs[c];
#pragma unroll
        for (int r = 0; r < 3; r++) {
            const __half* __restrict__ rp = outp + cb + yo[r];
            unsigned int cu = *reinterpret_cast<const unsigned int*>(rp);
            float2 ct = __half22float2(*(__half2*)&cu);
            float lf = __half2float(rp[loff]);
            float rt = __half2float(rp[2]);
            float k0 = dwks[c*9 + r*3 + 0] * my[r];
            float k1 = dwks[c*9 + r*3 + 1] * my[r];
            float k2 = dwks[c*9 + r*3 + 2] * my[r];
            rv0 += k0*(wl*lf) + k1*ct.x + k2*ct.y;
            rv1 += k0*ct.x + k1*ct.y + k2*(wr*rt);
        }
        __half2 hv = __floats2half2_rn(rv0, rv1);
        buf_s[c][l] = *(unsigned int*)&hv;
    }
    __syncthreads();

    // ---- phase 2: act = lrelu(pb1 + pw1 @ rv), acc in regs ----
    __half2 accA[4], accB[4];
#pragma unroll
    for (int q = 0; q < 4; q++) { accA[q] = pb1h[(c0 >> 1) + q]; accB[q] = accA[q]; }
#pragma unroll 8
    for (int c = 0; c < 64; c++) {
        unsigned int rvu = buf_s[c][l];
        __half2 rvp = *(__half2*)&rvu;
        __half2 r0 = __half2half2(__low2half(rvp));
        __half2 r1 = __half2half2(__high2half(rvp));
        uint4 wq = *reinterpret_cast<const uint4*>(&w1s[c][c0]);
        __half2 w01 = *(__half2*)&wq.x, w23 = *(__half2*)&wq.y;
        __half2 w45 = *(__half2*)&wq.z, w67 = *(__half2*)&wq.w;
        accA[0] = __hfma2(w01, r0, accA[0]); accB[0] = __hfma2(w01, r1, accB[0]);
        accA[1] = __hfma2(w23, r0, accA[1]); accB[1] = __hfma2(w23, r1, accB[1]);
        accA[2] = __hfma2(w45, r0, accA[2]); accB[2] = __hfma2(w45, r1, accB[2]);
        accA[3] = __hfma2(w67, r0, accA[3]); accB[3] = __hfma2(w67, r1, accB[3]);
    }
    __syncthreads();   // all rv reads done before act overwrites buf_s

#pragma unroll
    for (int q = 0; q < 4; q++) {
        float2 a0 = __half22float2(accA[q]);
        float2 a1 = __half22float2(accB[q]);
        float e0 = a0.x > 0.f ? a0.x : 0.2f*a0.x;
        float e1 = a0.y > 0.f ? a0.y : 0.2f*a0.y;
        float e2 = a1.x > 0.f ? a1.x : 0.2f*a1.x;
        float e3 = a1.y > 0.f ? a1.y : 0.2f*a1.y;
        __half2 p0 = __floats2half2_rn(e0, e2);
        __half2 p1 = __floats2half2_rn(e1, e3);
        buf_s[c0 + 2*q][l]     = *(unsigned int*)&p0;
        buf_s[c0 + 2*q + 1][l] = *(unsigned int*)&p1;
    }
    __syncthreads();

    // ---- phase 3: out = outp + ls * (pb2 + pw2 @ act) ----
#pragma unroll
    for (int q = 0; q < 4; q++) { accA[q] = pb2h[(c0 >> 1) + q]; accB[q] = accA[q]; }
#pragma unroll 8
    for (int j = 0; j < 64; j++) {
        unsigned int au = buf_s[j][l];
        __half2 ap = *(__half2*)&au;
        __half2 a0 = __half2half2(__low2half(ap));
        __half2 a1 = __half2half2(__high2half(ap));
        uint4 wq = *reinterpret_cast<const uint4*>(&w2s[j][c0]);
        __half2 w01 = *(__half2*)&wq.x, w23 = *(__half2*)&wq.y;
        __half2 w45 = *(__half2*)&wq.z, w67 = *(__half2*)&wq.w;
        accA[0] = __hfma2(w01, a0, accA[0]); accB[0] = __hfma2(w01, a1, accB[0]);
        accA[1] = __hfma2(w23, a0, accA[1]); accB[1] = __hfma2(w23, a1, accB[1]);
        accA[2] = __hfma2(w45, a0, accA[2]); accB[2] = __hfma2(w45, a1, accB[2]);
        accA[3] = __hfma2(w67, a0, accA[3]); accB[3] = __hfma2(w67, a1, accB[3]);
    }
#pragma unroll
    for (int q = 0; q < 4; q++) {
        float2 a0 = __half22float2(accA[q]);
        float2 a1 = __half22float2(accB[q]);
        int ca = c0 + 2*q, cb2 = ca + 1;
        int ba = base + ca*HWn + px0;
        int bb = base + cb2*HWn + px0;
        unsigned int oua = *reinterpret_cast<const unsigned int*>(outp + ba);
        unsigned int oub = *reinterpret_cast<const unsigned int*>(outp + bb);
        float2 oa = __half22float2(*(__half2*)&oua);
        float2 ob = __half22float2(*(__half2*)&oub);
        float la = lss[ca], lb = lss[cb2];
        *reinterpret_cast<float2*>(out + ba) = make_float2(oa.x + la*a0.x, oa.y + la*a1.x);
        *reinterpret_cast<float2*>(out + bb) = make_float2(ob.x + lb*a0.y, ob.y + lb*a1.y);
    }
}

extern "C" void kernel_launch(void* const* d_in, const int* in_sizes, int n_in,
                              void* d_out, int out_size, void* d_ws, size_t ws_size,
                              hipStream_t stream)
{
    (void)in_sizes; (void)n_in; (void)out_size; (void)ws_size;
    const float* force   = (const float*)d_in[0];
    const float* style   = (const float*)d_in[1];
    const float* illum   = (const float*)d_in[2];
    const float* h_w1    = (const float*)d_in[3];
    const float* h_b1    = (const float*)d_in[4];
    const float* h_w2    = (const float*)d_in[5];
    const float* h_b2    = (const float*)d_in[6];
    const float* h_w3    = (const float*)d_in[7];
    const float* h_b3    = (const float*)d_in[8];
    const float* dw_k    = (const float*)d_in[9];
    const float* pw_w    = (const float*)d_in[10];
    const float* r_dw_k  = (const float*)d_in[11];
    const float* r_dw_b  = (const float*)d_in[12];
    const float* r_pw1_w = (const float*)d_in[13];
    const float* r_pw1_b = (const float*)d_in[14];
    const float* r_pw2_w = (const float*)d_in[15];
    const float* r_pw2_b = (const float*)d_in[16];
    const float* lscale  = (const float*)d_in[17];

    float* out  = (float*)d_out;
    float* Xf32 = out + (size_t)NTOT;         // final x fp32
    float* Vf32 = out + 2*(size_t)NTOT;       // final v fp32

    char* w = (char*)d_ws;
    __half2* AB = (__half2*)w; w += (size_t)NTOT*4;
    __half*  F  = (__half*)w;  w += (size_t)NTOT*2;
    __half*  XA = (__half*)w;  w += (size_t)NTOT*2;
    __half*  XB = (__half*)w;  w += (size_t)NTOT*2;
    __half*  Vh = (__half*)w;  w += (size_t)NTOT*2;
    __half*  U2h = (__half*)w; w += (size_t)NPIX*32*2;   // 8.4 MB
    float* w1T  = (float*)w;
    float* c1   = w1T + 2048;
    float* pwT  = c1 + 32;
    float* pw1T = pwT + 4096;
    float* pw2T = pw1T + 4096;
    float* mu   = pw2T + 4096;
    float* rs   = mu + 512;
    __half2* w3abP = (__half2*)(rs + 512);
    __half2* w3gbP = w3abP + 2048;
    __half2* b3abP = w3gbP + 2048;
    __half2* b3gbP = b3abP + 64;
    float* Gsum = (float*)(b3gbP + 64);
    float* Gsq  = Gsum + 512;
    __half* outp = (__half*)AB;               // AB dead after last osc step

    prep<<<1, 256, 0, stream>>>(style, h_w1, h_b1, pw_w, r_pw1_w, r_pw2_w, h_w3, h_b3,
                                w1T, c1, pwT, pw1T, pw2T, w3abP, w3gbP, b3abP, b3gbP,
                                Gsum, Gsq);
    hyperU<<<NPIX/256, 256, 0, stream>>>((const float4*)force, (const float4*)illum,
                                         w1T, c1, h_w2, h_b2, F, XA, Vh, U2h);
    hyperA<<<dim3(NPIX/256, 2), 256, 0, stream>>>(U2h, w3abP, b3abP, AB);
    for (int s = 1; s <= 8; s++) {
        const __half* xin = (s & 1) ? XA : XB;
        __half*      xout = (s & 1) ? XB : XA;
        osc_step<false><<<2048, 256, 0, stream>>>(xin, xout, Vh, F, AB,
                                                  dw_k, pwT, nullptr, nullptr,
                                                  nullptr, nullptr);
    }
    // step 9 (odd): reads XA, writes fp32 x,v to d_out + fused inorm partial sums
    osc_step<true><<<2048, 256, 0, stream>>>(XA, XB, Vh, F, AB,
                                             dw_k, pwT, Xf32, Vf32, Gsum, Gsq);
    inorm_fin<<<2, 256, 0, stream>>>(Gsum, Gsq, mu, rs);
    modGB<<<dim3(NPIX/256, 4), 256, 0, stream>>>(U2h, F, Xf32, w3gbP, b3gbP,
                                                 mu, rs, outp);
    refine<<<NPIX/128, 512, 0, stream>>>(outp, r_dw_k, r_dw_b, pw1T, r_pw1_b,
                                         pw2T, r_pw2_b, lscale, out);
}